// Round 6
// baseline (286.036 us; speedup 1.0000x reference)
//
#include <hip/hip_runtime.h>

#define DEVFN static __device__ __forceinline__

constexpr int HHH = 262144;   // 64^3
constexpr int HH  = 4096;     // 64^2

typedef __attribute__((ext_vector_type(8))) short short8;
typedef __attribute__((ext_vector_type(4))) float f32x4;

// workspace layout (float offsets) — NO aliases: each region has one producer.
#define OFF_HX   ((size_t)0)
#define OFF_SP3  (OFF_HX   + 2*(size_t)HHH)
#define OFF_SP5A (OFF_SP3  + 2*(size_t)HHH)
#define OFF_SP5B (OFF_SP5A + 2*(size_t)HHH)
#define OFF_HXO  (OFF_SP5B + 2*(size_t)HHH)
#define OFF_Q    (OFF_HXO  + 2*(size_t)HHH)
#define OFF_K    (OFF_Q    + 2*(size_t)HH)
#define OFF_V    (OFF_K    + 2*(size_t)HH)
#define OFF_XYZ  (OFF_V    + 2*(size_t)HH)
#define OFF_KM   (OFF_XYZ  + 2*(size_t)HH)
#define OFF_Z    (OFF_KM   + 16)

DEVFN unsigned short f2bf(float f)
{
    unsigned u = __builtin_bit_cast(unsigned, f);
    u += 0x7fffu + ((u >> 16) & 1u);          // RNE
    return (unsigned short)(u >> 16);
}

// stage a 10x10x18 input tile (halo 1) for output tile 8x8x16 at (z0,y0,x0)
DEVFN void stage1800(const float* __restrict__ src, float* __restrict__ tile,
                     int z0, int y0, int x0, int tid)
{
    for (int i = tid; i < 1800; i += 256) {
        int lz = i / 180;
        int r  = i - lz * 180;
        int ly = r / 18;
        int lx = r - ly * 18;
        int gz = z0 - 1 + lz, gy = y0 - 1 + ly, gx = x0 - 1 + lx;
        float v = 0.f;
        if ((unsigned)(gz | gy | gx) < 64u)
            v = src[(gz * 64 + gy) * 64 + gx];
        tile[i] = v;
    }
}

// accumulate one channel's 27-tap conv for 4 consecutive-x voxels
DEVFN float4 conv27(const float* __restrict__ tile, int tz, int ty, int txg,
                    const float* __restrict__ wc, float4 acc)
{
#pragma unroll
    for (int dz = 0; dz < 3; ++dz) {
#pragma unroll
        for (int dy = 0; dy < 3; ++dy) {
            const float2* row = (const float2*)&tile[((tz + dz) * 10 + (ty + dy)) * 18 + txg * 4];
            float2 p0 = row[0], p1 = row[1], p2 = row[2];
            const float* wr = wc + (dz * 3 + dy) * 3;
            float w0 = wr[0], w1 = wr[1], w2 = wr[2];
            acc.x = fmaf(p0.x, w0, fmaf(p0.y, w1, fmaf(p1.x, w2, acc.x)));
            acc.y = fmaf(p0.y, w0, fmaf(p1.x, w1, fmaf(p1.y, w2, acc.y)));
            acc.z = fmaf(p1.x, w0, fmaf(p1.y, w1, fmaf(p2.x, w2, acc.z)));
            acc.w = fmaf(p1.y, w0, fmaf(p2.x, w1, fmaf(p2.y, w2, acc.w)));
        }
    }
    return acc;
}

// ---- conv_red: 32ch -> 1ch 3^3 conv, single-stage, prefetch double-buffer --
__global__ __launch_bounds__(256) void k_conv_red32(
    const float* __restrict__ x1, const float* __restrict__ x2,
    const float* __restrict__ w, const float* __restrict__ bias,
    float* __restrict__ hx)
{
    __shared__ __align__(16) float buf[2][1080];   // 6 x 10 x 18
    const int tid = threadIdx.x;
    const int tz = tid >> 6, ty = (tid >> 3) & 7, tx2 = tid & 7;
    const int bz = blockIdx.z;                      // b*16 + zq
    const int b = bz >> 4, z0 = (bz & 15) * 4;
    const int y0 = blockIdx.y * 8, x0 = blockIdx.x * 16;

    int gofs[5];
    bool inb[5];
#pragma unroll
    for (int k = 0; k < 5; ++k) {
        int i = tid + k * 256;
        inb[k] = false; gofs[k] = 0;
        if (i < 1080) {
            int lz = i / 180, r = i - lz * 180, ly = r / 18, lx = r - ly * 18;
            int gz = z0 - 1 + lz, gy = y0 - 1 + ly, gx = x0 - 1 + lx;
            if ((unsigned)(gz | gy | gx) < 64u) {
                inb[k] = true;
                gofs[k] = (gz * 64 + gy) * 64 + gx;
            }
        }
    }

    {
        const float* s = x1 + (size_t)(b * 16) * HHH;
#pragma unroll
        for (int k = 0; k < 5; ++k) {
            int i = tid + k * 256;
            if (i < 1080) buf[0][i] = inb[k] ? s[gofs[k]] : 0.f;
        }
    }
    __syncthreads();

    float2 acc = {0.f, 0.f};
    for (int c = 0; c < 32; ++c) {
        float r[5];
        if (c < 31) {
            int cn = c + 1;
            const float* s = (cn < 16 ? x1 : x2) + (size_t)(b * 16 + (cn & 15)) * HHH;
#pragma unroll
            for (int k = 0; k < 5; ++k)
                r[k] = inb[k] ? s[gofs[k]] : 0.f;
        }
        const float* wc = w + c * 27;
        const float* tb = buf[c & 1];
#pragma unroll
        for (int dz = 0; dz < 3; ++dz) {
#pragma unroll
            for (int dy = 0; dy < 3; ++dy) {
                const float2* row = (const float2*)&tb[((tz + dz) * 10 + (ty + dy)) * 18 + tx2 * 2];
                float2 p0 = row[0], p1 = row[1];
                const float* wr = wc + (dz * 3 + dy) * 3;
                float w0 = wr[0], w1 = wr[1], w2 = wr[2];
                acc.x = fmaf(p0.x, w0, fmaf(p0.y, w1, fmaf(p1.x, w2, acc.x)));
                acc.y = fmaf(p0.y, w0, fmaf(p1.x, w1, fmaf(p1.y, w2, acc.y)));
            }
        }
        if (c < 31) {
#pragma unroll
            for (int k = 0; k < 5; ++k) {
                int i = tid + k * 256;
                if (i < 1080) buf[(c + 1) & 1][i] = r[k];
            }
        }
        __syncthreads();
    }
    float bv = bias[0];
    float2 o = {fmaxf(acc.x + bv, 0.f), fmaxf(acc.y + bv, 0.f)};
    size_t oidx = (size_t)b * HHH + ((size_t)(z0 + tz) * 64 + (y0 + ty)) * 64 + (x0 + tx2 * 2);
    *(float2*)&hx[oidx] = o;
}

// ---------------- generic 1ch -> 1ch 3^3 conv, pad 1, relu ------------------
__global__ __launch_bounds__(256) void k_conv1ch(
    const float* __restrict__ in, const float* __restrict__ w,
    const float* __restrict__ bias, float* __restrict__ outp)
{
    __shared__ __align__(16) float tile[1800];
    const int tid = threadIdx.x;
    const int tz = tid >> 5, ty = (tid >> 2) & 7, txg = tid & 3;
    const int b  = blockIdx.z >> 3;
    const int z0 = (blockIdx.z & 7) * 8, y0 = blockIdx.y * 8, x0 = blockIdx.x * 16;

    stage1800(in + (size_t)b * HHH, tile, z0, y0, x0, tid);
    __syncthreads();
    float4 acc = {0.f, 0.f, 0.f, 0.f};
    acc = conv27(tile, tz, ty, txg, w, acc);
    float bv = bias[0];
    float4 o = {fmaxf(acc.x + bv, 0.f), fmaxf(acc.y + bv, 0.f),
                fmaxf(acc.z + bv, 0.f), fmaxf(acc.w + bv, 0.f)};
    size_t oidx = (size_t)b * HHH + ((size_t)(z0 + tz) * 64 + (y0 + ty)) * 64 + (x0 + txg * 4);
    *(float4*)&outp[oidx] = o;
}

// ---- dual 1ch conv: sp3 and sp5a from the same staged HX tile --------------
__global__ __launch_bounds__(256) void k_conv1ch_dual(
    const float* __restrict__ in,
    const float* __restrict__ wa, const float* __restrict__ ba, float* __restrict__ oa,
    const float* __restrict__ wb, const float* __restrict__ bb, float* __restrict__ ob)
{
    __shared__ __align__(16) float tile[1800];
    const int tid = threadIdx.x;
    const int tz = tid >> 5, ty = (tid >> 2) & 7, txg = tid & 3;
    const int b  = blockIdx.z >> 3;
    const int z0 = (blockIdx.z & 7) * 8, y0 = blockIdx.y * 8, x0 = blockIdx.x * 16;

    stage1800(in + (size_t)b * HHH, tile, z0, y0, x0, tid);
    __syncthreads();
    float4 zero = {0.f, 0.f, 0.f, 0.f};
    float4 aA = conv27(tile, tz, ty, txg, wa, zero);
    float4 aB = conv27(tile, tz, ty, txg, wb, zero);
    float bva = ba[0], bvb = bb[0];
    float4 ra = {fmaxf(aA.x + bva, 0.f), fmaxf(aA.y + bva, 0.f),
                 fmaxf(aA.z + bva, 0.f), fmaxf(aA.w + bva, 0.f)};
    float4 rb = {fmaxf(aB.x + bvb, 0.f), fmaxf(aB.y + bvb, 0.f),
                 fmaxf(aB.z + bvb, 0.f), fmaxf(aB.w + bvb, 0.f)};
    size_t oidx = (size_t)b * HHH + ((size_t)(z0 + tz) * 64 + (y0 + ty)) * 64 + (x0 + txg * 4);
    *(float4*)&oa[oidx] = ra;
    *(float4*)&ob[oidx] = rb;
}

// ---- Q,K: block per (b,i), direct reads (L2-resident), quad-lane reduce ----
__global__ __launch_bounds__(256) void k_qk(
    const float* __restrict__ hx,
    const float* __restrict__ wq, const float* __restrict__ bq,
    const float* __restrict__ wk, const float* __restrict__ bk,
    float* __restrict__ Q, float* __restrict__ K)
{
    const int bi = blockIdx.x;                 // b*64 + i
    const float* src = hx + (size_t)bi * HH;
    const int tid = threadIdx.x;
    const int j = tid >> 2, q = tid & 3;

    float a = 0.f;
    const float4* sv = (const float4*)(src + j * 64 + q * 16);
#pragma unroll
    for (int k = 0; k < 4; ++k) {
        float4 vv = sv[k];
        a = fmaf(vv.x, wq[q * 16 + k * 4 + 0], a);
        a = fmaf(vv.y, wq[q * 16 + k * 4 + 1], a);
        a = fmaf(vv.z, wq[q * 16 + k * 4 + 2], a);
        a = fmaf(vv.w, wq[q * 16 + k * 4 + 3], a);
    }
    a += __shfl_xor(a, 1); a += __shfl_xor(a, 2);

    float c = 0.f;
#pragma unroll
    for (int jj = 0; jj < 16; ++jj)
        c = fmaf(src[(q * 16 + jj) * 64 + j], wk[q * 16 + jj], c);
    c += __shfl_xor(c, 1); c += __shfl_xor(c, 2);

    if (q == 0) {
        Q[(size_t)bi * 64 + j] = fmaxf(a + bq[0], 0.f);
        K[(size_t)bi * 64 + j] = fmaxf(c + bk[0], 0.f);
    }
}

// ---- V: block per (b,t) -----------------------------------------------------
__global__ __launch_bounds__(256) void k_v(
    const float* __restrict__ hx, const float* __restrict__ wv,
    const float* __restrict__ bv, float* __restrict__ V)
{
    const int bt = blockIdx.x;     // b*64 + t
    const int b = bt >> 6, t = bt & 63;
    const int tid = threadIdx.x;
    const int j = tid >> 2, q = tid & 3;
    const float* src = hx + (size_t)b * HHH + (size_t)j * 64 + t;
    float a = 0.f;
#pragma unroll
    for (int k = 0; k < 16; ++k) {
        int i = q * 16 + k;
        a = fmaf(src[(size_t)i * HH], wv[i], a);
    }
    a += __shfl_xor(a, 1); a += __shfl_xor(a, 2);
    if (q == 0)
        V[(size_t)b * HH + t * 64 + j] = fmaxf(a + bv[0], 0.f);
}

__global__ void k_kmax(const float* __restrict__ K, float* __restrict__ kmax)
{
    __shared__ float red[256];
    int b = blockIdx.x;
    float m = -1e30f;
    for (int u = threadIdx.x; u < 4096; u += 256) m = fmaxf(m, K[b * 4096 + u]);
    red[threadIdx.x] = m;
    __syncthreads();
    for (int s = 128; s > 0; s >>= 1) {
        if (threadIdx.x < s) red[threadIdx.x] = fmaxf(red[threadIdx.x], red[threadIdx.x + s]);
        __syncthreads();
    }
    if (threadIdx.x == 0) kmax[b] = red[0];
}

// xyz[b,s] = sum_u softmax_u(Q[s]*K[u]) * V[u]   (Q >= 0 so max = Q*Kmax)
__global__ __launch_bounds__(256) void k_xyz(
    const float* __restrict__ Q, const float* __restrict__ K,
    const float* __restrict__ V, const float* __restrict__ kmax,
    float* __restrict__ xyz)
{
    __shared__ float pden[4][64];
    __shared__ float pnum[4][64];
    const int b = blockIdx.y;
    const int chunk = blockIdx.x;          // 0..63
    const int lane = threadIdx.x & 63;
    const int wv = __builtin_amdgcn_readfirstlane(threadIdx.x >> 6);
    const int s = chunk * 64 + lane;
    const float qv = Q[b * 4096 + s];
    const float m = qv * kmax[b];
    const float* Kp = K + b * 4096 + wv * 1024;
    const float* Vp = V + b * 4096 + wv * 1024;
    float den = 0.f, num = 0.f;
#pragma unroll 4
    for (int u = 0; u < 1024; ++u) {
        float e = __expf(fmaf(qv, Kp[u], -m));
        den += e;
        num = fmaf(e, Vp[u], num);
    }
    pden[wv][lane] = den;
    pnum[wv][lane] = num;
    __syncthreads();
    if (threadIdx.x < 64) {
        float d = pden[0][lane] + pden[1][lane] + pden[2][lane] + pden[3][lane];
        float n = pnum[0][lane] + pnum[1][lane] + pnum[2][lane] + pnum[3][lane];
        xyz[b * 4096 + s] = n / d;
    }
}

DEVFN void mac16(const float4* __restrict__ base, int vb, float a, float* acc)
{
    float4 q0 = base[vb], q1 = base[vb + 1], q2 = base[vb + 2], q3 = base[vb + 3];
    float qq[16] = {q0.x, q0.y, q0.z, q0.w, q1.x, q1.y, q1.z, q1.w,
                    q2.x, q2.y, q2.z, q2.w, q3.x, q3.y, q3.z, q3.w};
#pragma unroll
    for (int k = 0; k < 16; ++k) acc[k] = fmaf(a, qq[k], acc[k]);
}

// per (b,i): attn = softmax(sp1 @ sp3) @ sp5 ; hxo = xyz + attn + hx
__global__ __launch_bounds__(256) void k_attn(
    const float* __restrict__ hx, const float* __restrict__ sp3,
    const float* __restrict__ sp5, const float* __restrict__ xyz,
    const float* __restrict__ w_sp1, const float* __restrict__ b_sp1,
    float* __restrict__ hxo)
{
    __shared__ __align__(16) float s1[64 * 65];
    __shared__ __align__(16) float s3[4096];
    __shared__ __align__(16) float s5[4096];
    const int tid = threadIdx.x;
    const int bi = blockIdx.x;                    // b*64 + i
    const size_t off = (size_t)bi * HH;
    const float w1 = w_sp1[0], bb = b_sp1[0];
    for (int idx = tid; idx < 4096; idx += 256) {
        float hv = hx[off + idx];
        s1[(idx >> 6) * 65 + (idx & 63)] = fmaxf(fmaf(w1, hv, bb), 0.f);
        s3[idx] = sp3[off + idx];
        s5[idx] = sp5[off + idx];
    }
    __syncthreads();
    const int j = tid >> 2, g = tid & 3, t0 = g * 16;
    float m[16];
#pragma unroll
    for (int k = 0; k < 16; ++k) m[k] = 0.f;
    const float4* s3v = (const float4*)s3;
    for (int r = 0; r < 64; ++r) {
        float a = s1[j * 65 + r];
        mac16(s3v, r * 16 + (t0 >> 2), a, m);
    }
    float mx = m[0];
#pragma unroll
    for (int k = 1; k < 16; ++k) mx = fmaxf(mx, m[k]);
    mx = fmaxf(mx, __shfl_xor(mx, 1));
    mx = fmaxf(mx, __shfl_xor(mx, 2));
    float e[16];
    float sum = 0.f;
#pragma unroll
    for (int k = 0; k < 16; ++k) { e[k] = __expf(m[k] - mx); sum += e[k]; }
    sum += __shfl_xor(sum, 1);
    sum += __shfl_xor(sum, 2);
    const float inv = 1.f / sum;
    __syncthreads();
#pragma unroll
    for (int k = 0; k < 16; ++k) s1[j * 65 + t0 + k] = e[k] * inv;
    __syncthreads();
    float acc[16];
#pragma unroll
    for (int k = 0; k < 16; ++k) acc[k] = 0.f;
    const float4* s5v = (const float4*)s5;
    for (int r = 0; r < 64; ++r) {
        float a = s1[j * 65 + r];
        mac16(s5v, r * 16 + (t0 >> 2), a, acc);
    }
    const float xv = xyz[(size_t)(bi >> 6) * HH + (size_t)(bi & 63) * 64 + j];
    const size_t ob = off + (size_t)j * 64 + t0;
#pragma unroll
    for (int k = 0; k < 16; ++k)
        hxo[ob + k] = xv + acc[k] + hx[ob + k];
}

// ---------------- fuse: g=conv_fus(hxo); sp=sigmoid(relu(g+bf)+x); z=x*(sp+2)
// Z layout: [b*2+half][vox][ci(16)] bf16 (voxel-major -> coalesced convc staging)
DEVFN float zcalc(float gg, float bf, float xv)
{
    float t = fmaxf(gg + bf, 0.f) + xv;
    float s = 1.f / (1.f + __expf(-t));
    return xv * (s + 2.f);
}

__global__ __launch_bounds__(256) void k_fuse_half(
    const float* __restrict__ hxo, const float* __restrict__ x1,
    const float* __restrict__ x2, const float* __restrict__ w_fus,
    const float* __restrict__ b_fus, unsigned short* __restrict__ Zb)
{
    __shared__ __align__(16) float tile[1800];
    const int tid = threadIdx.x;
    const int tz = tid >> 5, ty = (tid >> 2) & 7, txg = tid & 3;
    const int bz = blockIdx.z;               // ((b*2+half)<<3) | zt
    const int zt = bz & 7, bh = bz >> 3;
    const int b = bh >> 1, half = bh & 1;
    const int z0 = zt * 8, y0 = blockIdx.y * 8, x0 = blockIdx.x * 16;

    stage1800(hxo + (size_t)b * HHH, tile, z0, y0, x0, tid);
    __syncthreads();

    const size_t vox = ((size_t)(z0 + tz) * 64 + (y0 + ty)) * 64 + (x0 + txg * 4);
    const float* xbase = (half ? x2 : x1) + (size_t)(b * 16) * HHH + vox;
    const float* wbase = w_fus + (half * 16) * 27;
    const float* bbase = b_fus + half * 16;

    unsigned zp[4][8];                       // [voxel][ci pair] packed bf16x2
#pragma unroll
    for (int cc = 0; cc < 16; ++cc) {
        float4 g = {0.f, 0.f, 0.f, 0.f};
        g = conv27(tile, tz, ty, txg, wbase + cc * 27, g);
        float4 xv = *(const float4*)(xbase + (size_t)cc * HHH);
        float bf = bbase[cc];
        unsigned short z0v = f2bf(zcalc(g.x, bf, xv.x));
        unsigned short z1v = f2bf(zcalc(g.y, bf, xv.y));
        unsigned short z2v = f2bf(zcalc(g.z, bf, xv.z));
        unsigned short z3v = f2bf(zcalc(g.w, bf, xv.w));
        int p = cc >> 1;
        if ((cc & 1) == 0) {
            zp[0][p] = z0v; zp[1][p] = z1v; zp[2][p] = z2v; zp[3][p] = z3v;
        } else {
            zp[0][p] |= (unsigned)z0v << 16; zp[1][p] |= (unsigned)z1v << 16;
            zp[2][p] |= (unsigned)z2v << 16; zp[3][p] |= (unsigned)z3v << 16;
        }
    }
    unsigned short* zo = Zb + ((size_t)bh * HHH + vox) * 16;
#pragma unroll
    for (int v = 0; v < 4; ++v) {
        uint4 lo = {zp[v][0], zp[v][1], zp[v][2], zp[v][3]};
        uint4 hi = {zp[v][4], zp[v][5], zp[v][6], zp[v][7]};
        *(uint4*)(zo + v * 16)     = lo;
        *(uint4*)(zo + v * 16 + 8) = hi;
    }
}

// ---------------- c1/c2: 16ch -> 16ch 3^3 conv via bf16 MFMA ----------------
// Z is [bh][vox][ci]; LDS tile 6z x 10y x 18x x 16ci = 34.6 KB -> 4 blocks/CU.
__global__ __launch_bounds__(256) void k_convc_mfma(
    const unsigned short* __restrict__ Zb,
    const float* __restrict__ w1, const float* __restrict__ b1,
    const float* __restrict__ w2, const float* __restrict__ b2,
    float* __restrict__ out)
{
    __shared__ __align__(16) unsigned short tile[1080 * 16];   // 34560 B: [pos][ci]
    const int tid = threadIdx.x;
    const int lane = tid & 63;
    const int wvid = tid >> 6;
    const int bz = blockIdx.z;                      // b*32 + half*16 + zq
    const int b = bz >> 5, half = (bz >> 4) & 1, z0 = (bz & 15) * 4;
    const int y0 = blockIdx.y * 8, x0 = blockIdx.x * 16;
    const float* w = half ? w2 : w1;
    const float* bias = half ? b2 : b1;

    const int co = lane & 15;
    const int g = lane >> 4;
    const int cihalf = g & 1;
    const int tapsel = g >> 1;

    short8 wf[14];
#pragma unroll
    for (int t = 0; t < 14; ++t) {
        int tap = 2 * t + tapsel;
        short8 v = {0, 0, 0, 0, 0, 0, 0, 0};
        if (tap < 27) {
#pragma unroll
            for (int i = 0; i < 8; ++i)
                v[i] = (short)f2bf(w[(co * 16 + cihalf * 8 + i) * 27 + tap]);
        }
        wf[t] = v;
    }
    float bfrag[4];
#pragma unroll
    for (int r = 0; r < 4; ++r) bfrag[r] = bias[g * 4 + r];

    // ---- stage Z tile: coalesced 16B chunks, [pos][ci], 2160 half-chunks ----
    const unsigned short* zsrc = Zb + (size_t)(b * 2 + half) * HHH * 16;
    for (int i = tid; i < 2160; i += 256) {
        int pos = i >> 1, h = i & 1;
        int lz = pos / 180;
        int r2 = pos - lz * 180;
        int ly = r2 / 18, lx = r2 - ly * 18;
        int gz = z0 - 1 + lz, gy = y0 - 1 + ly, gx = x0 - 1 + lx;
        uint4 pk = {0u, 0u, 0u, 0u};
        if ((unsigned)(gz | gy | gx) < 64u) {
            size_t gvox = ((size_t)(gz * 64 + gy)) * 64 + gx;
            pk = *(const uint4*)(zsrc + gvox * 16 + h * 8);
        }
        *(uint4*)&tile[pos * 16 + h * 8] = pk;
    }
    __syncthreads();

    int offs[14];
#pragma unroll
    for (int t = 0; t < 14; ++t) {
        int tap = 2 * t + tapsel;
        int tcl = tap < 27 ? tap : 26;
        int dz = tcl / 9, rr = tcl - dz * 9;
        int dy = rr / 3, dx = rr - dy * 3;
        offs[t] = (((dz * 10 + dy) * 18 + dx + (lane & 15)) << 5) + (cihalf << 4);
    }

    const char* tb = (const char*)tile;
    for (int rr = 0; rr < 8; ++rr) {                 // 32 rows / 4 waves
        int rowid = wvid * 8 + rr;
        int zr = rowid >> 3, yr = rowid & 7;
        int rbase = ((zr * 10 + yr) * 18) << 5;
        f32x4 acc = {0.f, 0.f, 0.f, 0.f};
        f32x4 acc2 = {0.f, 0.f, 0.f, 0.f};
#pragma unroll
        for (int t = 0; t < 14; t += 2) {
            short8 bf0 = *(const short8*)(tb + (rbase + offs[t]));
            acc = __builtin_amdgcn_mfma_f32_16x16x32_bf16(wf[t], bf0, acc, 0, 0, 0);
            short8 bf1 = *(const short8*)(tb + (rbase + offs[t + 1]));
            acc2 = __builtin_amdgcn_mfma_f32_16x16x32_bf16(wf[t + 1], bf1, acc2, 0, 0, 0);
        }
        size_t vox = ((size_t)(z0 + zr) * 64 + (y0 + yr)) * 64 + x0 + (lane & 15);
        float* ob = out + (size_t)half * (2 * 16 * (size_t)HHH) + (size_t)(b * 16) * HHH + vox;
#pragma unroll
        for (int r = 0; r < 4; ++r) {
            float v = acc[r] + acc2[r] + bfrag[r];
            ob[(size_t)(g * 4 + r) * HHH] = fmaxf(v, 0.f);
        }
    }
}

extern "C" void kernel_launch(void* const* d_in, const int* in_sizes, int n_in,
                              void* d_out, int out_size, void* d_ws, size_t ws_size,
                              hipStream_t stream)
{
    const float* x1     = (const float*)d_in[0];
    const float* x2     = (const float*)d_in[1];
    const float* w_red  = (const float*)d_in[2];
    const float* b_red  = (const float*)d_in[3];
    const float* w_cx   = (const float*)d_in[4];
    const float* b_cx   = (const float*)d_in[5];
    const float* w_cy   = (const float*)d_in[6];
    const float* b_cy   = (const float*)d_in[7];
    const float* w_cz   = (const float*)d_in[8];
    const float* b_cz   = (const float*)d_in[9];
    const float* w_sp1  = (const float*)d_in[10];
    const float* b_sp1  = (const float*)d_in[11];
    const float* w_sp3  = (const float*)d_in[12];
    const float* b_sp3  = (const float*)d_in[13];
    const float* w_sp5a = (const float*)d_in[14];
    const float* b_sp5a = (const float*)d_in[15];
    const float* w_sp5b = (const float*)d_in[16];
    const float* b_sp5b = (const float*)d_in[17];
    const float* w_fus  = (const float*)d_in[18];
    const float* b_fus  = (const float*)d_in[19];
    const float* w_c1   = (const float*)d_in[20];
    const float* b_c1   = (const float*)d_in[21];
    const float* w_c2   = (const float*)d_in[22];
    const float* b_c2   = (const float*)d_in[23];

    float* ws  = (float*)d_ws;
    float* out = (float*)d_out;

    float* HX   = ws + OFF_HX;
    float* SP3  = ws + OFF_SP3;
    float* SP5A = ws + OFF_SP5A;
    float* SP5B = ws + OFF_SP5B;
    float* HXO  = ws + OFF_HXO;
    float* Qb   = ws + OFF_Q;
    float* Kb   = ws + OFF_K;
    float* Vb   = ws + OFF_V;
    float* XYZb = ws + OFF_XYZ;
    float* KM   = ws + OFF_KM;
    unsigned short* Zb = (unsigned short*)(ws + OFF_Z);

    k_conv_red32<<<dim3(4, 8, 32), 256, 0, stream>>>(x1, x2, w_red, b_red, HX);
    k_conv1ch_dual<<<dim3(4, 8, 16), 256, 0, stream>>>(HX, w_sp3, b_sp3, SP3,
                                                       w_sp5a, b_sp5a, SP5A);
    k_conv1ch  <<<dim3(4, 8, 16), 256, 0, stream>>>(SP5A, w_sp5b, b_sp5b, SP5B);
    k_qk       <<<128, 256, 0, stream>>>(HX, w_cx, b_cx, w_cy, b_cy, Qb, Kb);
    k_v        <<<128, 256, 0, stream>>>(HX, w_cz, b_cz, Vb);
    k_kmax     <<<2, 256, 0, stream>>>(Kb, KM);
    k_xyz      <<<dim3(64, 2), 256, 0, stream>>>(Qb, Kb, Vb, KM, XYZb);
    k_attn     <<<128, 256, 0, stream>>>(HX, SP3, SP5B, XYZb, w_sp1, b_sp1, HXO);
    k_fuse_half<<<dim3(4, 8, 32), 256, 0, stream>>>(HXO, x1, x2, w_fus, b_fus, Zb);
    k_convc_mfma<<<dim3(4, 8, 64), 256, 0, stream>>>(Zb, w_c1, b_c1, w_c2, b_c2, out);
}

// Round 9
// 206.510 us; speedup vs baseline: 1.3851x; 1.3851x over previous
//
#include <hip/hip_runtime.h>

#define DEVFN static __device__ __forceinline__

constexpr int HHH = 262144;   // 64^3
constexpr int HH  = 4096;     // 64^2

typedef __attribute__((ext_vector_type(8))) short short8;
typedef __attribute__((ext_vector_type(4))) float f32x4;

// workspace layout (float offsets) — NO aliases: each region has one producer.
// Z (bf16 [4][HHH][16]) spans 32*HHH floats; WPRE sits strictly past it.
#define OFF_HX   ((size_t)0)
#define OFF_SP3  (OFF_HX   + 2*(size_t)HHH)
#define OFF_SP5A (OFF_SP3  + 2*(size_t)HHH)
#define OFF_SP5B (OFF_SP5A + 2*(size_t)HHH)
#define OFF_HXO  (OFF_SP5B + 2*(size_t)HHH)
#define OFF_Q    (OFF_HXO  + 2*(size_t)HHH)
#define OFF_K    (OFF_Q    + 2*(size_t)HH)
#define OFF_V    (OFF_K    + 2*(size_t)HH)
#define OFF_XYZ  (OFF_V    + 2*(size_t)HH)
#define OFF_KM   (OFF_XYZ  + 2*(size_t)HH)
#define OFF_Z    (OFF_KM   + 16)
#define OFF_WPRE (OFF_Z    + 32*(size_t)HHH)   // past Z's full bf16 extent

DEVFN unsigned short f2bf(float f)
{
    unsigned u = __builtin_bit_cast(unsigned, f);
    u += 0x7fffu + ((u >> 16) & 1u);          // RNE
    return (unsigned short)(u >> 16);
}

// stage a 10x10x18 input tile (halo 1) for output tile 8x8x16 at (z0,y0,x0)
DEVFN void stage1800(const float* __restrict__ src, float* __restrict__ tile,
                     int z0, int y0, int x0, int tid)
{
    for (int i = tid; i < 1800; i += 256) {
        int lz = i / 180;
        int r  = i - lz * 180;
        int ly = r / 18;
        int lx = r - ly * 18;
        int gz = z0 - 1 + lz, gy = y0 - 1 + ly, gx = x0 - 1 + lx;
        float v = 0.f;
        if ((unsigned)(gz | gy | gx) < 64u)
            v = src[(gz * 64 + gy) * 64 + gx];
        tile[i] = v;
    }
}

// accumulate one channel's 27-tap conv for 4 consecutive-x voxels
DEVFN float4 conv27(const float* __restrict__ tile, int tz, int ty, int txg,
                    const float* __restrict__ wc, float4 acc)
{
#pragma unroll
    for (int dz = 0; dz < 3; ++dz) {
#pragma unroll
        for (int dy = 0; dy < 3; ++dy) {
            const float2* row = (const float2*)&tile[((tz + dz) * 10 + (ty + dy)) * 18 + txg * 4];
            float2 p0 = row[0], p1 = row[1], p2 = row[2];
            const float* wr = wc + (dz * 3 + dy) * 3;
            float w0 = wr[0], w1 = wr[1], w2 = wr[2];
            acc.x = fmaf(p0.x, w0, fmaf(p0.y, w1, fmaf(p1.x, w2, acc.x)));
            acc.y = fmaf(p0.y, w0, fmaf(p1.x, w1, fmaf(p1.y, w2, acc.y)));
            acc.z = fmaf(p1.x, w0, fmaf(p1.y, w1, fmaf(p2.x, w2, acc.z)));
            acc.w = fmaf(p1.y, w0, fmaf(p2.x, w1, fmaf(p2.y, w2, acc.w)));
        }
    }
    return acc;
}

// ---- precompute bf16 MFMA weight fragments: wpre[(half*14+t)*64+lane] ------
__global__ __launch_bounds__(256) void k_wprep(
    const float* __restrict__ w1, const float* __restrict__ w2,
    unsigned short* __restrict__ wpre)
{
    int item = blockIdx.x * 256 + threadIdx.x;      // 0..1791
    if (item >= 1792) return;
    int half = item / 896;
    int rem  = item - half * 896;
    int t = rem >> 6, lane = rem & 63;
    const float* w = half ? w2 : w1;
    int co = lane & 15, g = lane >> 4;
    int cihalf = g & 1, tapsel = g >> 1;
    int tap = 2 * t + tapsel;
    unsigned v[4] = {0u, 0u, 0u, 0u};
    if (tap < 27) {
#pragma unroll
        for (int p = 0; p < 4; ++p) {
            unsigned short lo = f2bf(w[(co * 16 + cihalf * 8 + 2 * p) * 27 + tap]);
            unsigned short hi = f2bf(w[(co * 16 + cihalf * 8 + 2 * p + 1) * 27 + tap]);
            v[p] = (unsigned)lo | ((unsigned)hi << 16);
        }
    }
    uint4 pk = {v[0], v[1], v[2], v[3]};
    ((uint4*)wpre)[item] = pk;
}

// ---- conv_red: 32ch -> 1ch 3^3 conv, single-stage, prefetch double-buffer --
__global__ __launch_bounds__(256) void k_conv_red32(
    const float* __restrict__ x1, const float* __restrict__ x2,
    const float* __restrict__ w, const float* __restrict__ bias,
    float* __restrict__ hx)
{
    __shared__ __align__(16) float buf[2][1080];   // 6 x 10 x 18
    const int tid = threadIdx.x;
    const int tz = tid >> 6, ty = (tid >> 3) & 7, tx2 = tid & 7;
    const int bz = blockIdx.z;                      // b*16 + zq
    const int b = bz >> 4, z0 = (bz & 15) * 4;
    const int y0 = blockIdx.y * 8, x0 = blockIdx.x * 16;

    int gofs[5];
    bool inb[5];
#pragma unroll
    for (int k = 0; k < 5; ++k) {
        int i = tid + k * 256;
        inb[k] = false; gofs[k] = 0;
        if (i < 1080) {
            int lz = i / 180, r = i - lz * 180, ly = r / 18, lx = r - ly * 18;
            int gz = z0 - 1 + lz, gy = y0 - 1 + ly, gx = x0 - 1 + lx;
            if ((unsigned)(gz | gy | gx) < 64u) {
                inb[k] = true;
                gofs[k] = (gz * 64 + gy) * 64 + gx;
            }
        }
    }

    {
        const float* s = x1 + (size_t)(b * 16) * HHH;
#pragma unroll
        for (int k = 0; k < 5; ++k) {
            int i = tid + k * 256;
            if (i < 1080) buf[0][i] = inb[k] ? s[gofs[k]] : 0.f;
        }
    }
    __syncthreads();

    float2 acc = {0.f, 0.f};
    for (int c = 0; c < 32; ++c) {
        float r[5];
        if (c < 31) {
            int cn = c + 1;
            const float* s = (cn < 16 ? x1 : x2) + (size_t)(b * 16 + (cn & 15)) * HHH;
#pragma unroll
            for (int k = 0; k < 5; ++k)
                r[k] = inb[k] ? s[gofs[k]] : 0.f;
        }
        const float* wc = w + c * 27;
        const float* tb = buf[c & 1];
#pragma unroll
        for (int dz = 0; dz < 3; ++dz) {
#pragma unroll
            for (int dy = 0; dy < 3; ++dy) {
                const float2* row = (const float2*)&tb[((tz + dz) * 10 + (ty + dy)) * 18 + tx2 * 2];
                float2 p0 = row[0], p1 = row[1];
                const float* wr = wc + (dz * 3 + dy) * 3;
                float w0 = wr[0], w1 = wr[1], w2 = wr[2];
                acc.x = fmaf(p0.x, w0, fmaf(p0.y, w1, fmaf(p1.x, w2, acc.x)));
                acc.y = fmaf(p0.y, w0, fmaf(p1.x, w1, fmaf(p1.y, w2, acc.y)));
            }
        }
        if (c < 31) {
#pragma unroll
            for (int k = 0; k < 5; ++k) {
                int i = tid + k * 256;
                if (i < 1080) buf[(c + 1) & 1][i] = r[k];
            }
        }
        __syncthreads();
    }
    float bv = bias[0];
    float2 o = {fmaxf(acc.x + bv, 0.f), fmaxf(acc.y + bv, 0.f)};
    size_t oidx = (size_t)b * HHH + ((size_t)(z0 + tz) * 64 + (y0 + ty)) * 64 + (x0 + tx2 * 2);
    *(float2*)&hx[oidx] = o;
}

// ---------------- generic 1ch -> 1ch 3^3 conv, pad 1, relu ------------------
__global__ __launch_bounds__(256) void k_conv1ch(
    const float* __restrict__ in, const float* __restrict__ w,
    const float* __restrict__ bias, float* __restrict__ outp)
{
    __shared__ __align__(16) float tile[1800];
    const int tid = threadIdx.x;
    const int tz = tid >> 5, ty = (tid >> 2) & 7, txg = tid & 3;
    const int b  = blockIdx.z >> 3;
    const int z0 = (blockIdx.z & 7) * 8, y0 = blockIdx.y * 8, x0 = blockIdx.x * 16;

    stage1800(in + (size_t)b * HHH, tile, z0, y0, x0, tid);
    __syncthreads();
    float4 acc = {0.f, 0.f, 0.f, 0.f};
    acc = conv27(tile, tz, ty, txg, w, acc);
    float bv = bias[0];
    float4 o = {fmaxf(acc.x + bv, 0.f), fmaxf(acc.y + bv, 0.f),
                fmaxf(acc.z + bv, 0.f), fmaxf(acc.w + bv, 0.f)};
    size_t oidx = (size_t)b * HHH + ((size_t)(z0 + tz) * 64 + (y0 + ty)) * 64 + (x0 + txg * 4);
    *(float4*)&outp[oidx] = o;
}

// ---- dual 1ch conv: sp3 and sp5a from the same staged HX tile --------------
__global__ __launch_bounds__(256) void k_conv1ch_dual(
    const float* __restrict__ in,
    const float* __restrict__ wa, const float* __restrict__ ba, float* __restrict__ oa,
    const float* __restrict__ wb, const float* __restrict__ bb, float* __restrict__ ob)
{
    __shared__ __align__(16) float tile[1800];
    const int tid = threadIdx.x;
    const int tz = tid >> 5, ty = (tid >> 2) & 7, txg = tid & 3;
    const int b  = blockIdx.z >> 3;
    const int z0 = (blockIdx.z & 7) * 8, y0 = blockIdx.y * 8, x0 = blockIdx.x * 16;

    stage1800(in + (size_t)b * HHH, tile, z0, y0, x0, tid);
    __syncthreads();
    float4 zero = {0.f, 0.f, 0.f, 0.f};
    float4 aA = conv27(tile, tz, ty, txg, wa, zero);
    float4 aB = conv27(tile, tz, ty, txg, wb, zero);
    float bva = ba[0], bvb = bb[0];
    float4 ra = {fmaxf(aA.x + bva, 0.f), fmaxf(aA.y + bva, 0.f),
                 fmaxf(aA.z + bva, 0.f), fmaxf(aA.w + bva, 0.f)};
    float4 rb = {fmaxf(aB.x + bvb, 0.f), fmaxf(aB.y + bvb, 0.f),
                 fmaxf(aB.z + bvb, 0.f), fmaxf(aB.w + bvb, 0.f)};
    size_t oidx = (size_t)b * HHH + ((size_t)(z0 + tz) * 64 + (y0 + ty)) * 64 + (x0 + txg * 4);
    *(float4*)&oa[oidx] = ra;
    *(float4*)&ob[oidx] = rb;
}

// ---- Q,K: block per (b,i), direct reads (L2-resident), quad-lane reduce ----
__global__ __launch_bounds__(256) void k_qk(
    const float* __restrict__ hx,
    const float* __restrict__ wq, const float* __restrict__ bq,
    const float* __restrict__ wk, const float* __restrict__ bk,
    float* __restrict__ Q, float* __restrict__ K)
{
    const int bi = blockIdx.x;                 // b*64 + i
    const float* src = hx + (size_t)bi * HH;
    const int tid = threadIdx.x;
    const int j = tid >> 2, q = tid & 3;

    float a = 0.f;
    const float4* sv = (const float4*)(src + j * 64 + q * 16);
#pragma unroll
    for (int k = 0; k < 4; ++k) {
        float4 vv = sv[k];
        a = fmaf(vv.x, wq[q * 16 + k * 4 + 0], a);
        a = fmaf(vv.y, wq[q * 16 + k * 4 + 1], a);
        a = fmaf(vv.z, wq[q * 16 + k * 4 + 2], a);
        a = fmaf(vv.w, wq[q * 16 + k * 4 + 3], a);
    }
    a += __shfl_xor(a, 1); a += __shfl_xor(a, 2);

    float c = 0.f;
#pragma unroll
    for (int jj = 0; jj < 16; ++jj)
        c = fmaf(src[(q * 16 + jj) * 64 + j], wk[q * 16 + jj], c);
    c += __shfl_xor(c, 1); c += __shfl_xor(c, 2);

    if (q == 0) {
        Q[(size_t)bi * 64 + j] = fmaxf(a + bq[0], 0.f);
        K[(size_t)bi * 64 + j] = fmaxf(c + bk[0], 0.f);
    }
}

// ---- V: block per (b,t) -----------------------------------------------------
__global__ __launch_bounds__(256) void k_v(
    const float* __restrict__ hx, const float* __restrict__ wv,
    const float* __restrict__ bv, float* __restrict__ V)
{
    const int bt = blockIdx.x;     // b*64 + t
    const int b = bt >> 6, t = bt & 63;
    const int tid = threadIdx.x;
    const int j = tid >> 2, q = tid & 3;
    const float* src = hx + (size_t)b * HHH + (size_t)j * 64 + t;
    float a = 0.f;
#pragma unroll
    for (int k = 0; k < 16; ++k) {
        int i = q * 16 + k;
        a = fmaf(src[(size_t)i * HH], wv[i], a);
    }
    a += __shfl_xor(a, 1); a += __shfl_xor(a, 2);
    if (q == 0)
        V[(size_t)b * HH + t * 64 + j] = fmaxf(a + bv[0], 0.f);
}

__global__ void k_kmax(const float* __restrict__ K, float* __restrict__ kmax)
{
    __shared__ float red[256];
    int b = blockIdx.x;
    float m = -1e30f;
    for (int u = threadIdx.x; u < 4096; u += 256) m = fmaxf(m, K[b * 4096 + u]);
    red[threadIdx.x] = m;
    __syncthreads();
    for (int s = 128; s > 0; s >>= 1) {
        if (threadIdx.x < s) red[threadIdx.x] = fmaxf(red[threadIdx.x], red[threadIdx.x + s]);
        __syncthreads();
    }
    if (threadIdx.x == 0) kmax[b] = red[0];
}

// xyz[b,s] = sum_u softmax_u(Q[s]*K[u]) * V[u]   (Q >= 0 so max = Q*Kmax)
__global__ __launch_bounds__(256) void k_xyz(
    const float* __restrict__ Q, const float* __restrict__ K,
    const float* __restrict__ V, const float* __restrict__ kmax,
    float* __restrict__ xyz)
{
    __shared__ float pden[4][64];
    __shared__ float pnum[4][64];
    const int b = blockIdx.y;
    const int chunk = blockIdx.x;          // 0..63
    const int lane = threadIdx.x & 63;
    const int wv = __builtin_amdgcn_readfirstlane(threadIdx.x >> 6);
    const int s = chunk * 64 + lane;
    const float qv = Q[b * 4096 + s];
    const float m = qv * kmax[b];
    const float* Kp = K + b * 4096 + wv * 1024;
    const float* Vp = V + b * 4096 + wv * 1024;
    float den = 0.f, num = 0.f;
#pragma unroll 4
    for (int u = 0; u < 1024; ++u) {
        float e = __expf(fmaf(qv, Kp[u], -m));
        den += e;
        num = fmaf(e, Vp[u], num);
    }
    pden[wv][lane] = den;
    pnum[wv][lane] = num;
    __syncthreads();
    if (threadIdx.x < 64) {
        float d = pden[0][lane] + pden[1][lane] + pden[2][lane] + pden[3][lane];
        float n = pnum[0][lane] + pnum[1][lane] + pnum[2][lane] + pnum[3][lane];
        xyz[b * 4096 + s] = n / d;
    }
}

DEVFN void mac16(const float4* __restrict__ base, int vb, float a, float* acc)
{
    float4 q0 = base[vb], q1 = base[vb + 1], q2 = base[vb + 2], q3 = base[vb + 3];
    float qq[16] = {q0.x, q0.y, q0.z, q0.w, q1.x, q1.y, q1.z, q1.w,
                    q2.x, q2.y, q2.z, q2.w, q3.x, q3.y, q3.z, q3.w};
#pragma unroll
    for (int k = 0; k < 16; ++k) acc[k] = fmaf(a, qq[k], acc[k]);
}

// per (b,i): attn = softmax(sp1 @ sp3) @ sp5 ; hxo = xyz + attn + hx
__global__ __launch_bounds__(256) void k_attn(
    const float* __restrict__ hx, const float* __restrict__ sp3,
    const float* __restrict__ sp5, const float* __restrict__ xyz,
    const float* __restrict__ w_sp1, const float* __restrict__ b_sp1,
    float* __restrict__ hxo)
{
    __shared__ __align__(16) float s1[64 * 65];
    __shared__ __align__(16) float s3[4096];
    __shared__ __align__(16) float s5[4096];
    const int tid = threadIdx.x;
    const int bi = blockIdx.x;                    // b*64 + i
    const size_t off = (size_t)bi * HH;
    const float w1 = w_sp1[0], bb = b_sp1[0];
    for (int idx = tid; idx < 4096; idx += 256) {
        float hv = hx[off + idx];
        s1[(idx >> 6) * 65 + (idx & 63)] = fmaxf(fmaf(w1, hv, bb), 0.f);
        s3[idx] = sp3[off + idx];
        s5[idx] = sp5[off + idx];
    }
    __syncthreads();
    const int j = tid >> 2, g = tid & 3, t0 = g * 16;
    float m[16];
#pragma unroll
    for (int k = 0; k < 16; ++k) m[k] = 0.f;
    const float4* s3v = (const float4*)s3;
    for (int r = 0; r < 64; ++r) {
        float a = s1[j * 65 + r];
        mac16(s3v, r * 16 + (t0 >> 2), a, m);
    }
    float mx = m[0];
#pragma unroll
    for (int k = 1; k < 16; ++k) mx = fmaxf(mx, m[k]);
    mx = fmaxf(mx, __shfl_xor(mx, 1));
    mx = fmaxf(mx, __shfl_xor(mx, 2));
    float e[16];
    float sum = 0.f;
#pragma unroll
    for (int k = 0; k < 16; ++k) { e[k] = __expf(m[k] - mx); sum += e[k]; }
    sum += __shfl_xor(sum, 1);
    sum += __shfl_xor(sum, 2);
    const float inv = 1.f / sum;
    __syncthreads();
#pragma unroll
    for (int k = 0; k < 16; ++k) s1[j * 65 + t0 + k] = e[k] * inv;
    __syncthreads();
    float acc[16];
#pragma unroll
    for (int k = 0; k < 16; ++k) acc[k] = 0.f;
    const float4* s5v = (const float4*)s5;
    for (int r = 0; r < 64; ++r) {
        float a = s1[j * 65 + r];
        mac16(s5v, r * 16 + (t0 >> 2), a, acc);
    }
    const float xv = xyz[(size_t)(bi >> 6) * HH + (size_t)(bi & 63) * 64 + j];
    const size_t ob = off + (size_t)j * 64 + t0;
#pragma unroll
    for (int k = 0; k < 16; ++k)
        hxo[ob + k] = xv + acc[k] + hx[ob + k];
}

// ---------------- fuse: g=conv_fus(hxo); sp=sigmoid(relu(g+bf)+x); z=x*(sp+2)
// Z layout: [b*2+half][vox][ci(16)] bf16 (voxel-major -> coalesced convc staging)
DEVFN float zcalc(float gg, float bf, float xv)
{
    float t = fmaxf(gg + bf, 0.f) + xv;
    float s = 1.f / (1.f + __expf(-t));
    return xv * (s + 2.f);
}

__global__ __launch_bounds__(256) void k_fuse_half(
    const float* __restrict__ hxo, const float* __restrict__ x1,
    const float* __restrict__ x2, const float* __restrict__ w_fus,
    const float* __restrict__ b_fus, unsigned short* __restrict__ Zb)
{
    __shared__ __align__(16) float tile[1800];
    const int tid = threadIdx.x;
    const int tz = tid >> 5, ty = (tid >> 2) & 7, txg = tid & 3;
    const int bz = blockIdx.z;               // ((b*2+half)<<3) | zt
    const int zt = bz & 7, bh = bz >> 3;
    const int b = bh >> 1, half = bh & 1;
    const int z0 = zt * 8, y0 = blockIdx.y * 8, x0 = blockIdx.x * 16;

    stage1800(hxo + (size_t)b * HHH, tile, z0, y0, x0, tid);
    __syncthreads();

    const size_t vox = ((size_t)(z0 + tz) * 64 + (y0 + ty)) * 64 + (x0 + txg * 4);
    const float* xbase = (half ? x2 : x1) + (size_t)(b * 16) * HHH + vox;
    const float* wbase = w_fus + (half * 16) * 27;
    const float* bbase = b_fus + half * 16;

    unsigned zp[4][8];                       // [voxel][ci pair] packed bf16x2
#pragma unroll
    for (int cc = 0; cc < 16; ++cc) {
        float4 g = {0.f, 0.f, 0.f, 0.f};
        g = conv27(tile, tz, ty, txg, wbase + cc * 27, g);
        float4 xv = *(const float4*)(xbase + (size_t)cc * HHH);
        float bf = bbase[cc];
        unsigned short z0v = f2bf(zcalc(g.x, bf, xv.x));
        unsigned short z1v = f2bf(zcalc(g.y, bf, xv.y));
        unsigned short z2v = f2bf(zcalc(g.z, bf, xv.z));
        unsigned short z3v = f2bf(zcalc(g.w, bf, xv.w));
        int p = cc >> 1;
        if ((cc & 1) == 0) {
            zp[0][p] = z0v; zp[1][p] = z1v; zp[2][p] = z2v; zp[3][p] = z3v;
        } else {
            zp[0][p] |= (unsigned)z0v << 16; zp[1][p] |= (unsigned)z1v << 16;
            zp[2][p] |= (unsigned)z2v << 16; zp[3][p] |= (unsigned)z3v << 16;
        }
    }
    unsigned short* zo = Zb + ((size_t)bh * HHH + vox) * 16;
#pragma unroll
    for (int v = 0; v < 4; ++v) {
        uint4 lo = {zp[v][0], zp[v][1], zp[v][2], zp[v][3]};
        uint4 hi = {zp[v][4], zp[v][5], zp[v][6], zp[v][7]};
        *(uint4*)(zo + v * 16)     = lo;
        *(uint4*)(zo + v * 16 + 8) = hi;
    }
}

// ---------------- c1/c2: 16ch -> 16ch 3^3 conv via bf16 MFMA ----------------
// 512 threads, 8z tile (57.6KB LDS, 2 blocks/CU -> 16 waves/CU), precomputed wf.
__global__ __launch_bounds__(512) void k_convc_mfma(
    const unsigned short* __restrict__ Zb,
    const unsigned short* __restrict__ wpre,
    const float* __restrict__ b1, const float* __restrict__ b2,
    float* __restrict__ out)
{
    __shared__ __align__(16) unsigned short tile[1800 * 16];   // 57600 B: [pos][ci]
    const int tid = threadIdx.x;
    const int lane = tid & 63;
    const int wvid = tid >> 6;                      // 0..7
    const int bz = blockIdx.z;                      // b*16 + half*8 + zt, bz in [0,32)
    const int b = bz >> 4, half = (bz >> 3) & 1, z0 = (bz & 7) * 8;
    const int y0 = blockIdx.y * 8, x0 = blockIdx.x * 16;
    const float* bias = half ? b2 : b1;

    const int g = lane >> 4;
    const int cihalf = g & 1;
    const int tapsel = g >> 1;

    // ---- weight fragments: coalesced 16B loads from precomputed table ----
    short8 wf[14];
    const short8* wp = (const short8*)wpre + (half * 14) * 64 + lane;
#pragma unroll
    for (int t = 0; t < 14; ++t) wf[t] = wp[t * 64];

    float bfrag[4];
#pragma unroll
    for (int r = 0; r < 4; ++r) bfrag[r] = bias[g * 4 + r];

    // ---- stage Z tile: coalesced 16B chunks, [pos][ci] ----
    const unsigned short* zsrc = Zb + (size_t)(b * 2 + half) * HHH * 16;
    for (int i = tid; i < 3600; i += 512) {
        int pos = i >> 1, h = i & 1;
        int lz = pos / 180;
        int r2 = pos - lz * 180;
        int ly = r2 / 18, lx = r2 - ly * 18;
        int gz = z0 - 1 + lz, gy = y0 - 1 + ly, gx = x0 - 1 + lx;
        uint4 pk = {0u, 0u, 0u, 0u};
        if ((unsigned)(gz | gy | gx) < 64u) {
            size_t gvox = ((size_t)(gz * 64 + gy)) * 64 + gx;
            pk = *(const uint4*)(zsrc + gvox * 16 + h * 8);
        }
        *(uint4*)&tile[pos * 16 + h * 8] = pk;
    }
    __syncthreads();

    int offs[14];
#pragma unroll
    for (int t = 0; t < 14; ++t) {
        int tap = 2 * t + tapsel;
        int tcl = tap < 27 ? tap : 26;
        int dz = tcl / 9, rr = tcl - dz * 9;
        int dy = rr / 3, dx = rr - dy * 3;
        offs[t] = (((dz * 10 + dy) * 18 + dx + (lane & 15)) << 5) + (cihalf << 4);
    }

    const char* tb = (const char*)tile;
    for (int rr = 0; rr < 8; ++rr) {                 // 64 rows / 8 waves
        int rowid = wvid * 8 + rr;
        int zr = rowid >> 3, yr = rowid & 7;
        int rbase = ((zr * 10 + yr) * 18) << 5;
        f32x4 acc = {0.f, 0.f, 0.f, 0.f};
        f32x4 acc2 = {0.f, 0.f, 0.f, 0.f};
#pragma unroll
        for (int t = 0; t < 14; t += 2) {
            short8 bf0 = *(const short8*)(tb + (rbase + offs[t]));
            acc = __builtin_amdgcn_mfma_f32_16x16x32_bf16(wf[t], bf0, acc, 0, 0, 0);
            short8 bf1 = *(const short8*)(tb + (rbase + offs[t + 1]));
            acc2 = __builtin_amdgcn_mfma_f32_16x16x32_bf16(wf[t + 1], bf1, acc2, 0, 0, 0);
        }
        size_t vox = ((size_t)(z0 + zr) * 64 + (y0 + yr)) * 64 + x0 + (lane & 15);
        float* ob = out + (size_t)half * (2 * 16 * (size_t)HHH) + (size_t)(b * 16) * HHH + vox;
#pragma unroll
        for (int r = 0; r < 4; ++r) {
            float v = acc[r] + acc2[r] + bfrag[r];
            ob[(size_t)(g * 4 + r) * HHH] = fmaxf(v, 0.f);
        }
    }
}

extern "C" void kernel_launch(void* const* d_in, const int* in_sizes, int n_in,
                              void* d_out, int out_size, void* d_ws, size_t ws_size,
                              hipStream_t stream)
{
    const float* x1     = (const float*)d_in[0];
    const float* x2     = (const float*)d_in[1];
    const float* w_red  = (const float*)d_in[2];
    const float* b_red  = (const float*)d_in[3];
    const float* w_cx   = (const float*)d_in[4];
    const float* b_cx   = (const float*)d_in[5];
    const float* w_cy   = (const float*)d_in[6];
    const float* b_cy   = (const float*)d_in[7];
    const float* w_cz   = (const float*)d_in[8];
    const float* b_cz   = (const float*)d_in[9];
    const float* w_sp1  = (const float*)d_in[10];
    const float* b_sp1  = (const float*)d_in[11];
    const float* w_sp3  = (const float*)d_in[12];
    const float* b_sp3  = (const float*)d_in[13];
    const float* w_sp5a = (const float*)d_in[14];
    const float* b_sp5a = (const float*)d_in[15];
    const float* w_sp5b = (const float*)d_in[16];
    const float* b_sp5b = (const float*)d_in[17];
    const float* w_fus  = (const float*)d_in[18];
    const float* b_fus  = (const float*)d_in[19];
    const float* w_c1   = (const float*)d_in[20];
    const float* b_c1   = (const float*)d_in[21];
    const float* w_c2   = (const float*)d_in[22];
    const float* b_c2   = (const float*)d_in[23];

    float* ws  = (float*)d_ws;
    float* out = (float*)d_out;

    float* HX   = ws + OFF_HX;
    float* SP3  = ws + OFF_SP3;
    float* SP5A = ws + OFF_SP5A;
    float* SP5B = ws + OFF_SP5B;
    float* HXO  = ws + OFF_HXO;
    float* Qb   = ws + OFF_Q;
    float* Kb   = ws + OFF_K;
    float* Vb   = ws + OFF_V;
    float* XYZb = ws + OFF_XYZ;
    float* KM   = ws + OFF_KM;
    unsigned short* Zb   = (unsigned short*)(ws + OFF_Z);
    unsigned short* WPRE = (unsigned short*)(ws + OFF_WPRE);

    k_wprep    <<<7, 256, 0, stream>>>(w_c1, w_c2, WPRE);
    k_conv_red32<<<dim3(4, 8, 32), 256, 0, stream>>>(x1, x2, w_red, b_red, HX);
    k_conv1ch_dual<<<dim3(4, 8, 16), 256, 0, stream>>>(HX, w_sp3, b_sp3, SP3,
                                                       w_sp5a, b_sp5a, SP5A);
    k_conv1ch  <<<dim3(4, 8, 16), 256, 0, stream>>>(SP5A, w_sp5b, b_sp5b, SP5B);
    k_qk       <<<128, 256, 0, stream>>>(HX, w_cx, b_cx, w_cy, b_cy, Qb, Kb);
    k_v        <<<128, 256, 0, stream>>>(HX, w_cz, b_cz, Vb);
    k_kmax     <<<2, 256, 0, stream>>>(Kb, KM);
    k_xyz      <<<dim3(64, 2), 256, 0, stream>>>(Qb, Kb, Vb, KM, XYZb);
    k_attn     <<<128, 256, 0, stream>>>(HX, SP3, SP5B, XYZb, w_sp1, b_sp1, HXO);
    k_fuse_half<<<dim3(4, 8, 32), 256, 0, stream>>>(HXO, x1, x2, w_fus, b_fus, Zb);
    k_convc_mfma<<<dim3(4, 8, 32), 512, 0, stream>>>(Zb, WPRE, b_c1, b_c2, out);
}

// Round 10
// 205.247 us; speedup vs baseline: 1.3936x; 1.0062x over previous
//
#include <hip/hip_runtime.h>

#define DEVFN static __device__ __forceinline__

constexpr int HHH = 262144;   // 64^3
constexpr int HH  = 4096;     // 64^2
constexpr int RP  = 19;       // padded LDS row stride (odd -> banks spread)

typedef __attribute__((ext_vector_type(8))) short short8;
typedef __attribute__((ext_vector_type(4))) float f32x4;

// workspace layout (float offsets) — NO aliases: each region has one producer.
// Z (bf16 [4][HHH][16]) spans 32*HHH floats; WPRE sits strictly past it.
#define OFF_HX   ((size_t)0)
#define OFF_SP3  (OFF_HX   + 2*(size_t)HHH)
#define OFF_SP5A (OFF_SP3  + 2*(size_t)HHH)
#define OFF_SP5B (OFF_SP5A + 2*(size_t)HHH)
#define OFF_HXO  (OFF_SP5B + 2*(size_t)HHH)
#define OFF_Q    (OFF_HXO  + 2*(size_t)HHH)
#define OFF_K    (OFF_Q    + 2*(size_t)HH)
#define OFF_V    (OFF_K    + 2*(size_t)HH)
#define OFF_XYZ  (OFF_V    + 2*(size_t)HH)
#define OFF_KM   (OFF_XYZ  + 2*(size_t)HH)
#define OFF_Z    (OFF_KM   + 16)
#define OFF_WPRE (OFF_Z    + 32*(size_t)HHH)   // past Z's full bf16 extent

DEVFN unsigned short f2bf(float f)
{
    unsigned u = __builtin_bit_cast(unsigned, f);
    u += 0x7fffu + ((u >> 16) & 1u);          // RNE
    return (unsigned short)(u >> 16);
}

// stage a 10x10x18 input tile (halo 1) into padded [10][10][RP] layout
DEVFN void stage1800(const float* __restrict__ src, float* __restrict__ tile,
                     int z0, int y0, int x0, int tid)
{
    for (int i = tid; i < 1800; i += 256) {
        int lz = i / 180;
        int r  = i - lz * 180;
        int ly = r / 18;
        int lx = r - ly * 18;
        int gz = z0 - 1 + lz, gy = y0 - 1 + ly, gx = x0 - 1 + lx;
        float v = 0.f;
        if ((unsigned)(gz | gy | gx) < 64u)
            v = src[(gz * 64 + gy) * 64 + gx];
        tile[(lz * 10 + ly) * RP + lx] = v;
    }
}

// accumulate one channel's 27-tap conv for 4 consecutive-x voxels (padded tile)
DEVFN float4 conv27(const float* __restrict__ tile, int tz, int ty, int txg,
                    const float* __restrict__ wc, float4 acc)
{
#pragma unroll
    for (int dz = 0; dz < 3; ++dz) {
#pragma unroll
        for (int dy = 0; dy < 3; ++dy) {
            const float* row = &tile[((tz + dz) * 10 + (ty + dy)) * RP + txg * 4];
            float p0 = row[0], p1 = row[1], p2 = row[2];
            float p3 = row[3], p4 = row[4], p5 = row[5];
            const float* wr = wc + (dz * 3 + dy) * 3;
            float w0 = wr[0], w1 = wr[1], w2 = wr[2];
            acc.x = fmaf(p0, w0, fmaf(p1, w1, fmaf(p2, w2, acc.x)));
            acc.y = fmaf(p1, w0, fmaf(p2, w1, fmaf(p3, w2, acc.y)));
            acc.z = fmaf(p2, w0, fmaf(p3, w1, fmaf(p4, w2, acc.z)));
            acc.w = fmaf(p3, w0, fmaf(p4, w1, fmaf(p5, w2, acc.w)));
        }
    }
    return acc;
}

// ---- precompute bf16 MFMA weight fragments: wpre[(half*14+t)*64+lane] ------
__global__ __launch_bounds__(256) void k_wprep(
    const float* __restrict__ w1, const float* __restrict__ w2,
    unsigned short* __restrict__ wpre)
{
    int item = blockIdx.x * 256 + threadIdx.x;      // 0..1791
    if (item >= 1792) return;
    int half = item / 896;
    int rem  = item - half * 896;
    int t = rem >> 6, lane = rem & 63;
    const float* w = half ? w2 : w1;
    int co = lane & 15, g = lane >> 4;
    int cihalf = g & 1, tapsel = g >> 1;
    int tap = 2 * t + tapsel;
    unsigned v[4] = {0u, 0u, 0u, 0u};
    if (tap < 27) {
#pragma unroll
        for (int p = 0; p < 4; ++p) {
            unsigned short lo = f2bf(w[(co * 16 + cihalf * 8 + 2 * p) * 27 + tap]);
            unsigned short hi = f2bf(w[(co * 16 + cihalf * 8 + 2 * p + 1) * 27 + tap]);
            v[p] = (unsigned)lo | ((unsigned)hi << 16);
        }
    }
    uint4 pk = {v[0], v[1], v[2], v[3]};
    ((uint4*)wpre)[item] = pk;
}

// ---- conv_red: 32ch -> 1ch 3^3 conv, depth-2 prefetch, 3 LDS buffers -------
// 1024 blocks; tile 4z x 8y x 16x; padded rows (RP) kill bank conflicts.
__global__ __launch_bounds__(256) void k_conv_red32(
    const float* __restrict__ x1, const float* __restrict__ x2,
    const float* __restrict__ w, const float* __restrict__ bias,
    float* __restrict__ hx)
{
    __shared__ __align__(16) float buf[3][1140];   // 6 x 10 x RP
    const int tid = threadIdx.x;
    const int tz = tid >> 6, ty = (tid >> 3) & 7, tx2 = tid & 7;
    const int bz = blockIdx.z;                      // b*16 + zq
    const int b = bz >> 4, z0 = (bz & 15) * 4;
    const int y0 = blockIdx.y * 8, x0 = blockIdx.x * 16;

    int gofs[5], lidx[5];
    bool inb[5], act[5];
#pragma unroll
    for (int k = 0; k < 5; ++k) {
        int i = tid + k * 256;
        act[k] = (i < 1080);
        inb[k] = false; gofs[k] = 0; lidx[k] = 0;
        if (act[k]) {
            int lz = i / 180, r = i - lz * 180, ly = r / 18, lx = r - ly * 18;
            lidx[k] = (lz * 10 + ly) * RP + lx;
            int gz = z0 - 1 + lz, gy = y0 - 1 + ly, gx = x0 - 1 + lx;
            if ((unsigned)(gz | gy | gx) < 64u) {
                inb[k] = true;
                gofs[k] = (gz * 64 + gy) * 64 + gx;
            }
        }
    }

#define LOADCH(c, rdst)                                                         \
    {                                                                           \
        const float* s_ = ((c) < 16 ? x1 : x2) + (size_t)(b * 16 + ((c) & 15)) * HHH; \
        _Pragma("unroll")                                                       \
        for (int k = 0; k < 5; ++k) rdst[k] = (act[k] && inb[k]) ? s_[gofs[k]] : 0.f; \
    }
#define STORECH(buf_, rsrc)                                                     \
    {                                                                           \
        _Pragma("unroll")                                                       \
        for (int k = 0; k < 5; ++k) if (act[k]) (buf_)[lidx[k]] = rsrc[k];      \
    }

    float rcur[5], rnext[5];
    // prologue: ch0 -> buf0; issue ch1 loads
    LOADCH(0, rcur);
    STORECH(buf[0], rcur);
    LOADCH(1, rcur);
    __syncthreads();

    float2 acc = {0.f, 0.f};
    int cur = 0;
    for (int c = 0; c < 32; ++c) {
        if (c + 2 < 32) LOADCH(c + 2, rnext);       // issue early: hides under compute
        const float* wc = w + c * 27;
        const float* tb = buf[cur];
#pragma unroll
        for (int dz = 0; dz < 3; ++dz) {
#pragma unroll
            for (int dy = 0; dy < 3; ++dy) {
                const float* row = &tb[((tz + dz) * 10 + (ty + dy)) * RP + tx2 * 2];
                float p0 = row[0], p1 = row[1], p2 = row[2], p3 = row[3];
                const float* wr = wc + (dz * 3 + dy) * 3;
                float w0 = wr[0], w1 = wr[1], w2 = wr[2];
                acc.x = fmaf(p0, w0, fmaf(p1, w1, fmaf(p2, w2, acc.x)));
                acc.y = fmaf(p1, w0, fmaf(p2, w1, fmaf(p3, w2, acc.y)));
            }
        }
        int nxt = cur == 2 ? 0 : cur + 1;
        if (c + 1 < 32) {
            STORECH(buf[nxt], rcur);                // rcur loaded a full round ago
#pragma unroll
            for (int k = 0; k < 5; ++k) rcur[k] = rnext[k];
        }
        cur = nxt;
        __syncthreads();
    }
#undef LOADCH
#undef STORECH

    float bv = bias[0];
    float2 o = {fmaxf(acc.x + bv, 0.f), fmaxf(acc.y + bv, 0.f)};
    size_t oidx = (size_t)b * HHH + ((size_t)(z0 + tz) * 64 + (y0 + ty)) * 64 + (x0 + tx2 * 2);
    *(float2*)&hx[oidx] = o;
}

// ---------------- generic 1ch -> 1ch 3^3 conv, pad 1, relu ------------------
__global__ __launch_bounds__(256) void k_conv1ch(
    const float* __restrict__ in, const float* __restrict__ w,
    const float* __restrict__ bias, float* __restrict__ outp)
{
    __shared__ __align__(16) float tile[1900];
    const int tid = threadIdx.x;
    const int tz = tid >> 5, ty = (tid >> 2) & 7, txg = tid & 3;
    const int b  = blockIdx.z >> 3;
    const int z0 = (blockIdx.z & 7) * 8, y0 = blockIdx.y * 8, x0 = blockIdx.x * 16;

    stage1800(in + (size_t)b * HHH, tile, z0, y0, x0, tid);
    __syncthreads();
    float4 acc = {0.f, 0.f, 0.f, 0.f};
    acc = conv27(tile, tz, ty, txg, w, acc);
    float bv = bias[0];
    float4 o = {fmaxf(acc.x + bv, 0.f), fmaxf(acc.y + bv, 0.f),
                fmaxf(acc.z + bv, 0.f), fmaxf(acc.w + bv, 0.f)};
    size_t oidx = (size_t)b * HHH + ((size_t)(z0 + tz) * 64 + (y0 + ty)) * 64 + (x0 + txg * 4);
    *(float4*)&outp[oidx] = o;
}

// ---- dual 1ch conv: sp3 and sp5a from the same staged HX tile --------------
__global__ __launch_bounds__(256) void k_conv1ch_dual(
    const float* __restrict__ in,
    const float* __restrict__ wa, const float* __restrict__ ba, float* __restrict__ oa,
    const float* __restrict__ wb, const float* __restrict__ bb, float* __restrict__ ob)
{
    __shared__ __align__(16) float tile[1900];
    const int tid = threadIdx.x;
    const int tz = tid >> 5, ty = (tid >> 2) & 7, txg = tid & 3;
    const int b  = blockIdx.z >> 3;
    const int z0 = (blockIdx.z & 7) * 8, y0 = blockIdx.y * 8, x0 = blockIdx.x * 16;

    stage1800(in + (size_t)b * HHH, tile, z0, y0, x0, tid);
    __syncthreads();
    float4 zero = {0.f, 0.f, 0.f, 0.f};
    float4 aA = conv27(tile, tz, ty, txg, wa, zero);
    float4 aB = conv27(tile, tz, ty, txg, wb, zero);
    float bva = ba[0], bvb = bb[0];
    float4 ra = {fmaxf(aA.x + bva, 0.f), fmaxf(aA.y + bva, 0.f),
                 fmaxf(aA.z + bva, 0.f), fmaxf(aA.w + bva, 0.f)};
    float4 rb = {fmaxf(aB.x + bvb, 0.f), fmaxf(aB.y + bvb, 0.f),
                 fmaxf(aB.z + bvb, 0.f), fmaxf(aB.w + bvb, 0.f)};
    size_t oidx = (size_t)b * HHH + ((size_t)(z0 + tz) * 64 + (y0 + ty)) * 64 + (x0 + txg * 4);
    *(float4*)&oa[oidx] = ra;
    *(float4*)&ob[oidx] = rb;
}

// ---- Q,K: block per (b,i), direct reads (L2-resident), quad-lane reduce ----
__global__ __launch_bounds__(256) void k_qk(
    const float* __restrict__ hx,
    const float* __restrict__ wq, const float* __restrict__ bq,
    const float* __restrict__ wk, const float* __restrict__ bk,
    float* __restrict__ Q, float* __restrict__ K)
{
    const int bi = blockIdx.x;                 // b*64 + i
    const float* src = hx + (size_t)bi * HH;
    const int tid = threadIdx.x;
    const int j = tid >> 2, q = tid & 3;

    float a = 0.f;
    const float4* sv = (const float4*)(src + j * 64 + q * 16);
#pragma unroll
    for (int k = 0; k < 4; ++k) {
        float4 vv = sv[k];
        a = fmaf(vv.x, wq[q * 16 + k * 4 + 0], a);
        a = fmaf(vv.y, wq[q * 16 + k * 4 + 1], a);
        a = fmaf(vv.z, wq[q * 16 + k * 4 + 2], a);
        a = fmaf(vv.w, wq[q * 16 + k * 4 + 3], a);
    }
    a += __shfl_xor(a, 1); a += __shfl_xor(a, 2);

    float c = 0.f;
#pragma unroll
    for (int jj = 0; jj < 16; ++jj)
        c = fmaf(src[(q * 16 + jj) * 64 + j], wk[q * 16 + jj], c);
    c += __shfl_xor(c, 1); c += __shfl_xor(c, 2);

    if (q == 0) {
        Q[(size_t)bi * 64 + j] = fmaxf(a + bq[0], 0.f);
        K[(size_t)bi * 64 + j] = fmaxf(c + bk[0], 0.f);
    }
}

// ---- V: block per (b,t) -----------------------------------------------------
__global__ __launch_bounds__(256) void k_v(
    const float* __restrict__ hx, const float* __restrict__ wv,
    const float* __restrict__ bv, float* __restrict__ V)
{
    const int bt = blockIdx.x;     // b*64 + t
    const int b = bt >> 6, t = bt & 63;
    const int tid = threadIdx.x;
    const int j = tid >> 2, q = tid & 3;
    const float* src = hx + (size_t)b * HHH + (size_t)j * 64 + t;
    float a = 0.f;
#pragma unroll
    for (int k = 0; k < 16; ++k) {
        int i = q * 16 + k;
        a = fmaf(src[(size_t)i * HH], wv[i], a);
    }
    a += __shfl_xor(a, 1); a += __shfl_xor(a, 2);
    if (q == 0)
        V[(size_t)b * HH + t * 64 + j] = fmaxf(a + bv[0], 0.f);
}

__global__ void k_kmax(const float* __restrict__ K, float* __restrict__ kmax)
{
    __shared__ float red[256];
    int b = blockIdx.x;
    float m = -1e30f;
    for (int u = threadIdx.x; u < 4096; u += 256) m = fmaxf(m, K[b * 4096 + u]);
    red[threadIdx.x] = m;
    __syncthreads();
    for (int s = 128; s > 0; s >>= 1) {
        if (threadIdx.x < s) red[threadIdx.x] = fmaxf(red[threadIdx.x], red[threadIdx.x + s]);
        __syncthreads();
    }
    if (threadIdx.x == 0) kmax[b] = red[0];
}

// xyz[b,s] = sum_u softmax_u(Q[s]*K[u]) * V[u]   (Q >= 0 so max = Q*Kmax)
__global__ __launch_bounds__(256) void k_xyz(
    const float* __restrict__ Q, const float* __restrict__ K,
    const float* __restrict__ V, const float* __restrict__ kmax,
    float* __restrict__ xyz)
{
    __shared__ float pden[4][64];
    __shared__ float pnum[4][64];
    const int b = blockIdx.y;
    const int chunk = blockIdx.x;          // 0..63
    const int lane = threadIdx.x & 63;
    const int wv = __builtin_amdgcn_readfirstlane(threadIdx.x >> 6);
    const int s = chunk * 64 + lane;
    const float qv = Q[b * 4096 + s];
    const float m = qv * kmax[b];
    const float* Kp = K + b * 4096 + wv * 1024;
    const float* Vp = V + b * 4096 + wv * 1024;
    float den = 0.f, num = 0.f;
#pragma unroll 4
    for (int u = 0; u < 1024; ++u) {
        float e = __expf(fmaf(qv, Kp[u], -m));
        den += e;
        num = fmaf(e, Vp[u], num);
    }
    pden[wv][lane] = den;
    pnum[wv][lane] = num;
    __syncthreads();
    if (threadIdx.x < 64) {
        float d = pden[0][lane] + pden[1][lane] + pden[2][lane] + pden[3][lane];
        float n = pnum[0][lane] + pnum[1][lane] + pnum[2][lane] + pnum[3][lane];
        xyz[b * 4096 + s] = n / d;
    }
}

DEVFN void mac16(const float4* __restrict__ base, int vb, float a, float* acc)
{
    float4 q0 = base[vb], q1 = base[vb + 1], q2 = base[vb + 2], q3 = base[vb + 3];
    float qq[16] = {q0.x, q0.y, q0.z, q0.w, q1.x, q1.y, q1.z, q1.w,
                    q2.x, q2.y, q2.z, q2.w, q3.x, q3.y, q3.z, q3.w};
#pragma unroll
    for (int k = 0; k < 16; ++k) acc[k] = fmaf(a, qq[k], acc[k]);
}

// per (b,i): attn = softmax(sp1 @ sp3) @ sp5 ; hxo = xyz + attn + hx
__global__ __launch_bounds__(256) void k_attn(
    const float* __restrict__ hx, const float* __restrict__ sp3,
    const float* __restrict__ sp5, const float* __restrict__ xyz,
    const float* __restrict__ w_sp1, const float* __restrict__ b_sp1,
    float* __restrict__ hxo)
{
    __shared__ __align__(16) float s1[64 * 65];
    __shared__ __align__(16) float s3[4096];
    __shared__ __align__(16) float s5[4096];
    const int tid = threadIdx.x;
    const int bi = blockIdx.x;                    // b*64 + i
    const size_t off = (size_t)bi * HH;
    const float w1 = w_sp1[0], bb = b_sp1[0];
    for (int idx = tid; idx < 4096; idx += 256) {
        float hv = hx[off + idx];
        s1[(idx >> 6) * 65 + (idx & 63)] = fmaxf(fmaf(w1, hv, bb), 0.f);
        s3[idx] = sp3[off + idx];
        s5[idx] = sp5[off + idx];
    }
    __syncthreads();
    const int j = tid >> 2, g = tid & 3, t0 = g * 16;
    float m[16];
#pragma unroll
    for (int k = 0; k < 16; ++k) m[k] = 0.f;
    const float4* s3v = (const float4*)s3;
    for (int r = 0; r < 64; ++r) {
        float a = s1[j * 65 + r];
        mac16(s3v, r * 16 + (t0 >> 2), a, m);
    }
    float mx = m[0];
#pragma unroll
    for (int k = 1; k < 16; ++k) mx = fmaxf(mx, m[k]);
    mx = fmaxf(mx, __shfl_xor(mx, 1));
    mx = fmaxf(mx, __shfl_xor(mx, 2));
    float e[16];
    float sum = 0.f;
#pragma unroll
    for (int k = 0; k < 16; ++k) { e[k] = __expf(m[k] - mx); sum += e[k]; }
    sum += __shfl_xor(sum, 1);
    sum += __shfl_xor(sum, 2);
    const float inv = 1.f / sum;
    __syncthreads();
#pragma unroll
    for (int k = 0; k < 16; ++k) s1[j * 65 + t0 + k] = e[k] * inv;
    __syncthreads();
    float acc[16];
#pragma unroll
    for (int k = 0; k < 16; ++k) acc[k] = 0.f;
    const float4* s5v = (const float4*)s5;
    for (int r = 0; r < 64; ++r) {
        float a = s1[j * 65 + r];
        mac16(s5v, r * 16 + (t0 >> 2), a, acc);
    }
    const float xv = xyz[(size_t)(bi >> 6) * HH + (size_t)(bi & 63) * 64 + j];
    const size_t ob = off + (size_t)j * 64 + t0;
#pragma unroll
    for (int k = 0; k < 16; ++k)
        hxo[ob + k] = xv + acc[k] + hx[ob + k];
}

// ---------------- fuse: g=conv_fus(hxo); sp=sigmoid(relu(g+bf)+x); z=x*(sp+2)
// Z layout: [b*2+half][vox][ci(16)] bf16 (voxel-major -> coalesced convc staging)
DEVFN float zcalc(float gg, float bf, float xv)
{
    float t = fmaxf(gg + bf, 0.f) + xv;
    float s = 1.f / (1.f + __expf(-t));
    return xv * (s + 2.f);
}

__global__ __launch_bounds__(256) void k_fuse_half(
    const float* __restrict__ hxo, const float* __restrict__ x1,
    const float* __restrict__ x2, const float* __restrict__ w_fus,
    const float* __restrict__ b_fus, unsigned short* __restrict__ Zb)
{
    __shared__ __align__(16) float tile[1900];
    const int tid = threadIdx.x;
    const int tz = tid >> 5, ty = (tid >> 2) & 7, txg = tid & 3;
    const int bz = blockIdx.z;               // ((b*2+half)<<3) | zt
    const int zt = bz & 7, bh = bz >> 3;
    const int b = bh >> 1, half = bh & 1;
    const int z0 = zt * 8, y0 = blockIdx.y * 8, x0 = blockIdx.x * 16;

    stage1800(hxo + (size_t)b * HHH, tile, z0, y0, x0, tid);
    __syncthreads();

    const size_t vox = ((size_t)(z0 + tz) * 64 + (y0 + ty)) * 64 + (x0 + txg * 4);
    const float* xbase = (half ? x2 : x1) + (size_t)(b * 16) * HHH + vox;
    const float* wbase = w_fus + (half * 16) * 27;
    const float* bbase = b_fus + half * 16;

    unsigned zp[4][8];                       // [voxel][ci pair] packed bf16x2
#pragma unroll
    for (int cc = 0; cc < 16; ++cc) {
        float4 g = {0.f, 0.f, 0.f, 0.f};
        g = conv27(tile, tz, ty, txg, wbase + cc * 27, g);
        float4 xv = *(const float4*)(xbase + (size_t)cc * HHH);
        float bf = bbase[cc];
        unsigned short z0v = f2bf(zcalc(g.x, bf, xv.x));
        unsigned short z1v = f2bf(zcalc(g.y, bf, xv.y));
        unsigned short z2v = f2bf(zcalc(g.z, bf, xv.z));
        unsigned short z3v = f2bf(zcalc(g.w, bf, xv.w));
        int p = cc >> 1;
        if ((cc & 1) == 0) {
            zp[0][p] = z0v; zp[1][p] = z1v; zp[2][p] = z2v; zp[3][p] = z3v;
        } else {
            zp[0][p] |= (unsigned)z0v << 16; zp[1][p] |= (unsigned)z1v << 16;
            zp[2][p] |= (unsigned)z2v << 16; zp[3][p] |= (unsigned)z3v << 16;
        }
    }
    unsigned short* zo = Zb + ((size_t)bh * HHH + vox) * 16;
#pragma unroll
    for (int v = 0; v < 4; ++v) {
        uint4 lo = {zp[v][0], zp[v][1], zp[v][2], zp[v][3]};
        uint4 hi = {zp[v][4], zp[v][5], zp[v][6], zp[v][7]};
        *(uint4*)(zo + v * 16)     = lo;
        *(uint4*)(zo + v * 16 + 8) = hi;
    }
}

// ---------------- c1/c2: 16ch -> 16ch 3^3 conv via bf16 MFMA ----------------
// 512 threads, 8z tile (57.6KB LDS, 2 blocks/CU -> 16 waves/CU), precomputed wf.
__global__ __launch_bounds__(512) void k_convc_mfma(
    const unsigned short* __restrict__ Zb,
    const unsigned short* __restrict__ wpre,
    const float* __restrict__ b1, const float* __restrict__ b2,
    float* __restrict__ out)
{
    __shared__ __align__(16) unsigned short tile[1800 * 16];   // 57600 B: [pos][ci]
    const int tid = threadIdx.x;
    const int lane = tid & 63;
    const int wvid = tid >> 6;                      // 0..7
    const int bz = blockIdx.z;                      // b*16 + half*8 + zt, bz in [0,32)
    const int b = bz >> 4, half = (bz >> 3) & 1, z0 = (bz & 7) * 8;
    const int y0 = blockIdx.y * 8, x0 = blockIdx.x * 16;
    const float* bias = half ? b2 : b1;

    const int g = lane >> 4;
    const int cihalf = g & 1;
    const int tapsel = g >> 1;

    // ---- weight fragments: coalesced 16B loads from precomputed table ----
    short8 wf[14];
    const short8* wp = (const short8*)wpre + (half * 14) * 64 + lane;
#pragma unroll
    for (int t = 0; t < 14; ++t) wf[t] = wp[t * 64];

    float bfrag[4];
#pragma unroll
    for (int r = 0; r < 4; ++r) bfrag[r] = bias[g * 4 + r];

    // ---- stage Z tile: coalesced 16B chunks, [pos][ci] ----
    const unsigned short* zsrc = Zb + (size_t)(b * 2 + half) * HHH * 16;
    for (int i = tid; i < 3600; i += 512) {
        int pos = i >> 1, h = i & 1;
        int lz = pos / 180;
        int r2 = pos - lz * 180;
        int ly = r2 / 18, lx = r2 - ly * 18;
        int gz = z0 - 1 + lz, gy = y0 - 1 + ly, gx = x0 - 1 + lx;
        uint4 pk = {0u, 0u, 0u, 0u};
        if ((unsigned)(gz | gy | gx) < 64u) {
            size_t gvox = ((size_t)(gz * 64 + gy)) * 64 + gx;
            pk = *(const uint4*)(zsrc + gvox * 16 + h * 8);
        }
        *(uint4*)&tile[pos * 16 + h * 8] = pk;
    }
    __syncthreads();

    int offs[14];
#pragma unroll
    for (int t = 0; t < 14; ++t) {
        int tap = 2 * t + tapsel;
        int tcl = tap < 27 ? tap : 26;
        int dz = tcl / 9, rr = tcl - dz * 9;
        int dy = rr / 3, dx = rr - dy * 3;
        offs[t] = (((dz * 10 + dy) * 18 + dx + (lane & 15)) << 5) + (cihalf << 4);
    }

    const char* tb = (const char*)tile;
    for (int rr = 0; rr < 8; ++rr) {                 // 64 rows / 8 waves
        int rowid = wvid * 8 + rr;
        int zr = rowid >> 3, yr = rowid & 7;
        int rbase = ((zr * 10 + yr) * 18) << 5;
        f32x4 acc = {0.f, 0.f, 0.f, 0.f};
        f32x4 acc2 = {0.f, 0.f, 0.f, 0.f};
#pragma unroll
        for (int t = 0; t < 14; t += 2) {
            short8 bf0 = *(const short8*)(tb + (rbase + offs[t]));
            acc = __builtin_amdgcn_mfma_f32_16x16x32_bf16(wf[t], bf0, acc, 0, 0, 0);
            short8 bf1 = *(const short8*)(tb + (rbase + offs[t + 1]));
            acc2 = __builtin_amdgcn_mfma_f32_16x16x32_bf16(wf[t + 1], bf1, acc2, 0, 0, 0);
        }
        size_t vox = ((size_t)(z0 + zr) * 64 + (y0 + yr)) * 64 + x0 + (lane & 15);
        float* ob = out + (size_t)half * (2 * 16 * (size_t)HHH) + (size_t)(b * 16) * HHH + vox;
#pragma unroll
        for (int r = 0; r < 4; ++r) {
            float v = acc[r] + acc2[r] + bfrag[r];
            ob[(size_t)(g * 4 + r) * HHH] = fmaxf(v, 0.f);
        }
    }
}

extern "C" void kernel_launch(void* const* d_in, const int* in_sizes, int n_in,
                              void* d_out, int out_size, void* d_ws, size_t ws_size,
                              hipStream_t stream)
{
    const float* x1     = (const float*)d_in[0];
    const float* x2     = (const float*)d_in[1];
    const float* w_red  = (const float*)d_in[2];
    const float* b_red  = (const float*)d_in[3];
    const float* w_cx   = (const float*)d_in[4];
    const float* b_cx   = (const float*)d_in[5];
    const float* w_cy   = (const float*)d_in[6];
    const float* b_cy   = (const float*)d_in[7];
    const float* w_cz   = (const float*)d_in[8];
    const float* b_cz   = (const float*)d_in[9];
    const float* w_sp1  = (const float*)d_in[10];
    const float* b_sp1  = (const float*)d_in[11];
    const float* w_sp3  = (const float*)d_in[12];
    const float* b_sp3  = (const float*)d_in[13];
    const float* w_sp5a = (const float*)d_in[14];
    const float* b_sp5a = (const float*)d_in[15];
    const float* w_sp5b = (const float*)d_in[16];
    const float* b_sp5b = (const float*)d_in[17];
    const float* w_fus  = (const float*)d_in[18];
    const float* b_fus  = (const float*)d_in[19];
    const float* w_c1   = (const float*)d_in[20];
    const float* b_c1   = (const float*)d_in[21];
    const float* w_c2   = (const float*)d_in[22];
    const float* b_c2   = (const float*)d_in[23];

    float* ws  = (float*)d_ws;
    float* out = (float*)d_out;

    float* HX   = ws + OFF_HX;
    float* SP3  = ws + OFF_SP3;
    float* SP5A = ws + OFF_SP5A;
    float* SP5B = ws + OFF_SP5B;
    float* HXO  = ws + OFF_HXO;
    float* Qb   = ws + OFF_Q;
    float* Kb   = ws + OFF_K;
    float* Vb   = ws + OFF_V;
    float* XYZb = ws + OFF_XYZ;
    float* KM   = ws + OFF_KM;
    unsigned short* Zb   = (unsigned short*)(ws + OFF_Z);
    unsigned short* WPRE = (unsigned short*)(ws + OFF_WPRE);

    k_wprep    <<<7, 256, 0, stream>>>(w_c1, w_c2, WPRE);
    k_conv_red32<<<dim3(4, 8, 32), 256, 0, stream>>>(x1, x2, w_red, b_red, HX);
    k_conv1ch_dual<<<dim3(4, 8, 16), 256, 0, stream>>>(HX, w_sp3, b_sp3, SP3,
                                                       w_sp5a, b_sp5a, SP5A);
    k_conv1ch  <<<dim3(4, 8, 16), 256, 0, stream>>>(SP5A, w_sp5b, b_sp5b, SP5B);
    k_qk       <<<128, 256, 0, stream>>>(HX, w_cx, b_cx, w_cy, b_cy, Qb, Kb);
    k_v        <<<128, 256, 0, stream>>>(HX, w_cz, b_cz, Vb);
    k_kmax     <<<2, 256, 0, stream>>>(Kb, KM);
    k_xyz      <<<dim3(64, 2), 256, 0, stream>>>(Qb, Kb, Vb, KM, XYZb);
    k_attn     <<<128, 256, 0, stream>>>(HX, SP3, SP5B, XYZb, w_sp1, b_sp1, HXO);
    k_fuse_half<<<dim3(4, 8, 32), 256, 0, stream>>>(HXO, x1, x2, w_fus, b_fus, Zb);
    k_convc_mfma<<<dim3(4, 8, 32), 512, 0, stream>>>(Zb, WPRE, b_c1, b_c2, out);
}

// Round 11
// 205.095 us; speedup vs baseline: 1.3947x; 1.0007x over previous
//
#include <hip/hip_runtime.h>

#define DEVFN static __device__ __forceinline__

constexpr int HHH = 262144;   // 64^3
constexpr int HH  = 4096;     // 64^2
constexpr int SP  = 20;       // padded LDS row stride (mult of 4 -> b128-aligned)

typedef __attribute__((ext_vector_type(8))) short short8;
typedef __attribute__((ext_vector_type(4))) float f32x4;

// workspace layout (float offsets) — NO aliases: each region has one producer.
// Z (bf16 [4][HHH][16]) spans 32*HHH floats; WPRE sits strictly past it.
#define OFF_HX   ((size_t)0)
#define OFF_SP3  (OFF_HX   + 2*(size_t)HHH)
#define OFF_SP5A (OFF_SP3  + 2*(size_t)HHH)
#define OFF_SP5B (OFF_SP5A + 2*(size_t)HHH)
#define OFF_HXO  (OFF_SP5B + 2*(size_t)HHH)
#define OFF_Q    (OFF_HXO  + 2*(size_t)HHH)
#define OFF_K    (OFF_Q    + 2*(size_t)HH)
#define OFF_V    (OFF_K    + 2*(size_t)HH)
#define OFF_XYZ  (OFF_V    + 2*(size_t)HH)
#define OFF_KM   (OFF_XYZ  + 2*(size_t)HH)
#define OFF_Z    (OFF_KM   + 16)
#define OFF_WPRE (OFF_Z    + 32*(size_t)HHH)   // past Z's full bf16 extent

DEVFN unsigned short f2bf(float f)
{
    unsigned u = __builtin_bit_cast(unsigned, f);
    u += 0x7fffu + ((u >> 16) & 1u);          // RNE
    return (unsigned short)(u >> 16);
}

// stage a 10x10x18 input tile (halo 1) into padded [10][10][SP] layout
DEVFN void stage20(const float* __restrict__ src, float* __restrict__ tile,
                   int z0, int y0, int x0, int tid)
{
    for (int i = tid; i < 1800; i += 256) {
        int lz = i / 180;
        int r  = i - lz * 180;
        int ly = r / 18;
        int lx = r - ly * 18;
        int gz = z0 - 1 + lz, gy = y0 - 1 + ly, gx = x0 - 1 + lx;
        float v = 0.f;
        if ((unsigned)(gz | gy | gx) < 64u)
            v = src[(gz * 64 + gy) * 64 + gx];
        tile[(lz * 10 + ly) * SP + lx] = v;
    }
}

// load the 9-row x 6-float neighborhood for 4 consecutive-x voxels into regs
DEVFN void loadnb(const float* __restrict__ tile, int tz, int ty, int txg,
                  float4* pa, float2* pb)
{
#pragma unroll
    for (int dz = 0; dz < 3; ++dz) {
#pragma unroll
        for (int dy = 0; dy < 3; ++dy) {
            const float* row = &tile[((tz + dz) * 10 + (ty + dy)) * SP + txg * 4];
            pa[dz * 3 + dy] = *(const float4*)row;      // 16B-aligned (SP%4==0)
            pb[dz * 3 + dy] = *(const float2*)(row + 4);
        }
    }
}

// conv from register neighborhood (identical FMA order to prior conv27)
DEVFN float4 conv27r(const float4* pa, const float2* pb,
                     const float* __restrict__ wc, float4 acc)
{
#pragma unroll
    for (int t = 0; t < 9; ++t) {
        float w0 = wc[3 * t], w1 = wc[3 * t + 1], w2 = wc[3 * t + 2];
        float4 p = pa[t];
        float2 q = pb[t];
        acc.x = fmaf(p.x, w0, fmaf(p.y, w1, fmaf(p.z, w2, acc.x)));
        acc.y = fmaf(p.y, w0, fmaf(p.z, w1, fmaf(p.w, w2, acc.y)));
        acc.z = fmaf(p.z, w0, fmaf(p.w, w1, fmaf(q.x, w2, acc.z)));
        acc.w = fmaf(p.w, w0, fmaf(q.x, w1, fmaf(q.y, w2, acc.w)));
    }
    return acc;
}

// ---- precompute bf16 MFMA weight fragments: wpre[(half*14+t)*64+lane] ------
__global__ __launch_bounds__(256) void k_wprep(
    const float* __restrict__ w1, const float* __restrict__ w2,
    unsigned short* __restrict__ wpre)
{
    int item = blockIdx.x * 256 + threadIdx.x;      // 0..1791
    if (item >= 1792) return;
    int half = item / 896;
    int rem  = item - half * 896;
    int t = rem >> 6, lane = rem & 63;
    const float* w = half ? w2 : w1;
    int co = lane & 15, g = lane >> 4;
    int cihalf = g & 1, tapsel = g >> 1;
    int tap = 2 * t + tapsel;
    unsigned v[4] = {0u, 0u, 0u, 0u};
    if (tap < 27) {
#pragma unroll
        for (int p = 0; p < 4; ++p) {
            unsigned short lo = f2bf(w[(co * 16 + cihalf * 8 + 2 * p) * 27 + tap]);
            unsigned short hi = f2bf(w[(co * 16 + cihalf * 8 + 2 * p + 1) * 27 + tap]);
            v[p] = (unsigned)lo | ((unsigned)hi << 16);
        }
    }
    uint4 pk = {v[0], v[1], v[2], v[3]};
    ((uint4*)wpre)[item] = pk;
}

// ---- conv_red: 32ch -> 1ch 3^3, 8z tile, float4 outputs, vector LDS reads --
// 512 blocks (2/CU); depth-2 register prefetch over 3 LDS buffers.
__global__ __launch_bounds__(256) void k_conv_red32(
    const float* __restrict__ x1, const float* __restrict__ x2,
    const float* __restrict__ w, const float* __restrict__ bias,
    float* __restrict__ hx)
{
    __shared__ __align__(16) float buf[3][2000];   // 10 x 10 x SP
    const int tid = threadIdx.x;
    const int tz = tid >> 5, ty = (tid >> 2) & 7, txg = tid & 3;
    const int bz = blockIdx.z;                      // b*8 + zt
    const int b = bz >> 3, z0 = (bz & 7) * 8;
    const int y0 = blockIdx.y * 8, x0 = blockIdx.x * 16;

    int gofs[8], lidx[8];
    bool inb[8], act[8];
#pragma unroll
    for (int k = 0; k < 8; ++k) {
        int i = tid + k * 256;
        act[k] = (i < 1800);
        inb[k] = false; gofs[k] = 0; lidx[k] = 0;
        if (act[k]) {
            int lz = i / 180, r = i - lz * 180, ly = r / 18, lx = r - ly * 18;
            lidx[k] = (lz * 10 + ly) * SP + lx;
            int gz = z0 - 1 + lz, gy = y0 - 1 + ly, gx = x0 - 1 + lx;
            if ((unsigned)(gz | gy | gx) < 64u) {
                inb[k] = true;
                gofs[k] = (gz * 64 + gy) * 64 + gx;
            }
        }
    }

#define LOADCH(c, rdst)                                                         \
    {                                                                           \
        const float* s_ = ((c) < 16 ? x1 : x2) + (size_t)(b * 16 + ((c) & 15)) * HHH; \
        _Pragma("unroll")                                                       \
        for (int k = 0; k < 8; ++k) rdst[k] = (act[k] && inb[k]) ? s_[gofs[k]] : 0.f; \
    }
#define STORECH(buf_, rsrc)                                                     \
    {                                                                           \
        _Pragma("unroll")                                                       \
        for (int k = 0; k < 8; ++k) if (act[k]) (buf_)[lidx[k]] = rsrc[k];      \
    }

    float rcur[8], rnext[8];
    LOADCH(0, rcur);
    STORECH(buf[0], rcur);
    LOADCH(1, rcur);
    __syncthreads();

    float4 acc = {0.f, 0.f, 0.f, 0.f};
    int cur = 0;
    for (int c = 0; c < 32; ++c) {
        if (c + 2 < 32) LOADCH(c + 2, rnext);       // issue early: hides under compute
        const float* wc = w + c * 27;
        const float* tb = buf[cur];
#pragma unroll
        for (int dz = 0; dz < 3; ++dz) {
#pragma unroll
            for (int dy = 0; dy < 3; ++dy) {
                const float* row = &tb[((tz + dz) * 10 + (ty + dy)) * SP + txg * 4];
                float4 p = *(const float4*)row;
                float2 q = *(const float2*)(row + 4);
                const float* wr = wc + (dz * 3 + dy) * 3;
                float w0 = wr[0], w1 = wr[1], w2 = wr[2];
                acc.x = fmaf(p.x, w0, fmaf(p.y, w1, fmaf(p.z, w2, acc.x)));
                acc.y = fmaf(p.y, w0, fmaf(p.z, w1, fmaf(p.w, w2, acc.y)));
                acc.z = fmaf(p.z, w0, fmaf(p.w, w1, fmaf(q.x, w2, acc.z)));
                acc.w = fmaf(p.w, w0, fmaf(q.x, w1, fmaf(q.y, w2, acc.w)));
            }
        }
        int nxt = cur == 2 ? 0 : cur + 1;
        if (c + 1 < 32) {
            STORECH(buf[nxt], rcur);                // rcur loaded a full round ago
#pragma unroll
            for (int k = 0; k < 8; ++k) rcur[k] = rnext[k];
        }
        cur = nxt;
        __syncthreads();
    }
#undef LOADCH
#undef STORECH

    float bv = bias[0];
    float4 o = {fmaxf(acc.x + bv, 0.f), fmaxf(acc.y + bv, 0.f),
                fmaxf(acc.z + bv, 0.f), fmaxf(acc.w + bv, 0.f)};
    size_t oidx = (size_t)b * HHH + ((size_t)(z0 + tz) * 64 + (y0 + ty)) * 64 + (x0 + txg * 4);
    *(float4*)&hx[oidx] = o;
}

// ---------------- generic 1ch -> 1ch 3^3 conv, pad 1, relu ------------------
__global__ __launch_bounds__(256) void k_conv1ch(
    const float* __restrict__ in, const float* __restrict__ w,
    const float* __restrict__ bias, float* __restrict__ outp)
{
    __shared__ __align__(16) float tile[2000];
    const int tid = threadIdx.x;
    const int tz = tid >> 5, ty = (tid >> 2) & 7, txg = tid & 3;
    const int b  = blockIdx.z >> 3;
    const int z0 = (blockIdx.z & 7) * 8, y0 = blockIdx.y * 8, x0 = blockIdx.x * 16;

    stage20(in + (size_t)b * HHH, tile, z0, y0, x0, tid);
    __syncthreads();
    float4 pa[9]; float2 pb[9];
    loadnb(tile, tz, ty, txg, pa, pb);
    float4 acc = {0.f, 0.f, 0.f, 0.f};
    acc = conv27r(pa, pb, w, acc);
    float bv = bias[0];
    float4 o = {fmaxf(acc.x + bv, 0.f), fmaxf(acc.y + bv, 0.f),
                fmaxf(acc.z + bv, 0.f), fmaxf(acc.w + bv, 0.f)};
    size_t oidx = (size_t)b * HHH + ((size_t)(z0 + tz) * 64 + (y0 + ty)) * 64 + (x0 + txg * 4);
    *(float4*)&outp[oidx] = o;
}

// ---- dual 1ch conv: sp3 and sp5a from the same register neighborhood -------
__global__ __launch_bounds__(256) void k_conv1ch_dual(
    const float* __restrict__ in,
    const float* __restrict__ wa, const float* __restrict__ ba, float* __restrict__ oa,
    const float* __restrict__ wb, const float* __restrict__ bb, float* __restrict__ ob)
{
    __shared__ __align__(16) float tile[2000];
    const int tid = threadIdx.x;
    const int tz = tid >> 5, ty = (tid >> 2) & 7, txg = tid & 3;
    const int b  = blockIdx.z >> 3;
    const int z0 = (blockIdx.z & 7) * 8, y0 = blockIdx.y * 8, x0 = blockIdx.x * 16;

    stage20(in + (size_t)b * HHH, tile, z0, y0, x0, tid);
    __syncthreads();
    float4 pa[9]; float2 pb[9];
    loadnb(tile, tz, ty, txg, pa, pb);
    float4 zero = {0.f, 0.f, 0.f, 0.f};
    float4 aA = conv27r(pa, pb, wa, zero);
    float4 aB = conv27r(pa, pb, wb, zero);
    float bva = ba[0], bvb = bb[0];
    float4 ra = {fmaxf(aA.x + bva, 0.f), fmaxf(aA.y + bva, 0.f),
                 fmaxf(aA.z + bva, 0.f), fmaxf(aA.w + bva, 0.f)};
    float4 rb = {fmaxf(aB.x + bvb, 0.f), fmaxf(aB.y + bvb, 0.f),
                 fmaxf(aB.z + bvb, 0.f), fmaxf(aB.w + bvb, 0.f)};
    size_t oidx = (size_t)b * HHH + ((size_t)(z0 + tz) * 64 + (y0 + ty)) * 64 + (x0 + txg * 4);
    *(float4*)&oa[oidx] = ra;
    *(float4*)&ob[oidx] = rb;
}

// ---- Q,K: block per (b,i), direct reads (L2-resident), quad-lane reduce ----
__global__ __launch_bounds__(256) void k_qk(
    const float* __restrict__ hx,
    const float* __restrict__ wq, const float* __restrict__ bq,
    const float* __restrict__ wk, const float* __restrict__ bk,
    float* __restrict__ Q, float* __restrict__ K)
{
    const int bi = blockIdx.x;                 // b*64 + i
    const float* src = hx + (size_t)bi * HH;
    const int tid = threadIdx.x;
    const int j = tid >> 2, q = tid & 3;

    float a = 0.f;
    const float4* sv = (const float4*)(src + j * 64 + q * 16);
#pragma unroll
    for (int k = 0; k < 4; ++k) {
        float4 vv = sv[k];
        a = fmaf(vv.x, wq[q * 16 + k * 4 + 0], a);
        a = fmaf(vv.y, wq[q * 16 + k * 4 + 1], a);
        a = fmaf(vv.z, wq[q * 16 + k * 4 + 2], a);
        a = fmaf(vv.w, wq[q * 16 + k * 4 + 3], a);
    }
    a += __shfl_xor(a, 1); a += __shfl_xor(a, 2);

    float c = 0.f;
#pragma unroll
    for (int jj = 0; jj < 16; ++jj)
        c = fmaf(src[(q * 16 + jj) * 64 + j], wk[q * 16 + jj], c);
    c += __shfl_xor(c, 1); c += __shfl_xor(c, 2);

    if (q == 0) {
        Q[(size_t)bi * 64 + j] = fmaxf(a + bq[0], 0.f);
        K[(size_t)bi * 64 + j] = fmaxf(c + bk[0], 0.f);
    }
}

// ---- V: block per (b,t) -----------------------------------------------------
__global__ __launch_bounds__(256) void k_v(
    const float* __restrict__ hx, const float* __restrict__ wv,
    const float* __restrict__ bv, float* __restrict__ V)
{
    const int bt = blockIdx.x;     // b*64 + t
    const int b = bt >> 6, t = bt & 63;
    const int tid = threadIdx.x;
    const int j = tid >> 2, q = tid & 3;
    const float* src = hx + (size_t)b * HHH + (size_t)j * 64 + t;
    float a = 0.f;
#pragma unroll
    for (int k = 0; k < 16; ++k) {
        int i = q * 16 + k;
        a = fmaf(src[(size_t)i * HH], wv[i], a);
    }
    a += __shfl_xor(a, 1); a += __shfl_xor(a, 2);
    if (q == 0)
        V[(size_t)b * HH + t * 64 + j] = fmaxf(a + bv[0], 0.f);
}

__global__ void k_kmax(const float* __restrict__ K, float* __restrict__ kmax)
{
    __shared__ float red[256];
    int b = blockIdx.x;
    float m = -1e30f;
    for (int u = threadIdx.x; u < 4096; u += 256) m = fmaxf(m, K[b * 4096 + u]);
    red[threadIdx.x] = m;
    __syncthreads();
    for (int s = 128; s > 0; s >>= 1) {
        if (threadIdx.x < s) red[threadIdx.x] = fmaxf(red[threadIdx.x], red[threadIdx.x + s]);
        __syncthreads();
    }
    if (threadIdx.x == 0) kmax[b] = red[0];
}

// xyz[b,s] = sum_u softmax_u(Q[s]*K[u]) * V[u]   (Q >= 0 so max = Q*Kmax)
__global__ __launch_bounds__(256) void k_xyz(
    const float* __restrict__ Q, const float* __restrict__ K,
    const float* __restrict__ V, const float* __restrict__ kmax,
    float* __restrict__ xyz)
{
    __shared__ float pden[4][64];
    __shared__ float pnum[4][64];
    const int b = blockIdx.y;
    const int chunk = blockIdx.x;          // 0..63
    const int lane = threadIdx.x & 63;
    const int wv = __builtin_amdgcn_readfirstlane(threadIdx.x >> 6);
    const int s = chunk * 64 + lane;
    const float qv = Q[b * 4096 + s];
    const float m = qv * kmax[b];
    const float* Kp = K + b * 4096 + wv * 1024;
    const float* Vp = V + b * 4096 + wv * 1024;
    float den = 0.f, num = 0.f;
#pragma unroll 4
    for (int u = 0; u < 1024; ++u) {
        float e = __expf(fmaf(qv, Kp[u], -m));
        den += e;
        num = fmaf(e, Vp[u], num);
    }
    pden[wv][lane] = den;
    pnum[wv][lane] = num;
    __syncthreads();
    if (threadIdx.x < 64) {
        float d = pden[0][lane] + pden[1][lane] + pden[2][lane] + pden[3][lane];
        float n = pnum[0][lane] + pnum[1][lane] + pnum[2][lane] + pnum[3][lane];
        xyz[b * 4096 + s] = n / d;
    }
}

DEVFN void mac16(const float4* __restrict__ base, int vb, float a, float* acc)
{
    float4 q0 = base[vb], q1 = base[vb + 1], q2 = base[vb + 2], q3 = base[vb + 3];
    float qq[16] = {q0.x, q0.y, q0.z, q0.w, q1.x, q1.y, q1.z, q1.w,
                    q2.x, q2.y, q2.z, q2.w, q3.x, q3.y, q3.z, q3.w};
#pragma unroll
    for (int k = 0; k < 16; ++k) acc[k] = fmaf(a, qq[k], acc[k]);
}

// per (b,i): attn = softmax(sp1 @ sp3) @ sp5 ; hxo = xyz + attn + hx
__global__ __launch_bounds__(256) void k_attn(
    const float* __restrict__ hx, const float* __restrict__ sp3,
    const float* __restrict__ sp5, const float* __restrict__ xyz,
    const float* __restrict__ w_sp1, const float* __restrict__ b_sp1,
    float* __restrict__ hxo)
{
    __shared__ __align__(16) float s1[64 * 65];
    __shared__ __align__(16) float s3[4096];
    __shared__ __align__(16) float s5[4096];
    const int tid = threadIdx.x;
    const int bi = blockIdx.x;                    // b*64 + i
    const size_t off = (size_t)bi * HH;
    const float w1 = w_sp1[0], bb = b_sp1[0];
    for (int idx = tid; idx < 4096; idx += 256) {
        float hv = hx[off + idx];
        s1[(idx >> 6) * 65 + (idx & 63)] = fmaxf(fmaf(w1, hv, bb), 0.f);
        s3[idx] = sp3[off + idx];
        s5[idx] = sp5[off + idx];
    }
    __syncthreads();
    const int j = tid >> 2, g = tid & 3, t0 = g * 16;
    float m[16];
#pragma unroll
    for (int k = 0; k < 16; ++k) m[k] = 0.f;
    const float4* s3v = (const float4*)s3;
    for (int r = 0; r < 64; ++r) {
        float a = s1[j * 65 + r];
        mac16(s3v, r * 16 + (t0 >> 2), a, m);
    }
    float mx = m[0];
#pragma unroll
    for (int k = 1; k < 16; ++k) mx = fmaxf(mx, m[k]);
    mx = fmaxf(mx, __shfl_xor(mx, 1));
    mx = fmaxf(mx, __shfl_xor(mx, 2));
    float e[16];
    float sum = 0.f;
#pragma unroll
    for (int k = 0; k < 16; ++k) { e[k] = __expf(m[k] - mx); sum += e[k]; }
    sum += __shfl_xor(sum, 1);
    sum += __shfl_xor(sum, 2);
    const float inv = 1.f / sum;
    __syncthreads();
#pragma unroll
    for (int k = 0; k < 16; ++k) s1[j * 65 + t0 + k] = e[k] * inv;
    __syncthreads();
    float acc[16];
#pragma unroll
    for (int k = 0; k < 16; ++k) acc[k] = 0.f;
    const float4* s5v = (const float4*)s5;
    for (int r = 0; r < 64; ++r) {
        float a = s1[j * 65 + r];
        mac16(s5v, r * 16 + (t0 >> 2), a, acc);
    }
    const float xv = xyz[(size_t)(bi >> 6) * HH + (size_t)(bi & 63) * 64 + j];
    const size_t ob = off + (size_t)j * 64 + t0;
#pragma unroll
    for (int k = 0; k < 16; ++k)
        hxo[ob + k] = xv + acc[k] + hx[ob + k];
}

// ---------------- fuse: g=conv_fus(hxo); sp=sigmoid(relu(g+bf)+x); z=x*(sp+2)
// Z layout: [b*2+half][vox][ci(16)] bf16; neighborhood hoisted to registers.
DEVFN float zcalc(float gg, float bf, float xv)
{
    float t = fmaxf(gg + bf, 0.f) + xv;
    float s = 1.f / (1.f + __expf(-t));
    return xv * (s + 2.f);
}

__global__ __launch_bounds__(256) void k_fuse_half(
    const float* __restrict__ hxo, const float* __restrict__ x1,
    const float* __restrict__ x2, const float* __restrict__ w_fus,
    const float* __restrict__ b_fus, unsigned short* __restrict__ Zb)
{
    __shared__ __align__(16) float tile[2000];
    const int tid = threadIdx.x;
    const int tz = tid >> 5, ty = (tid >> 2) & 7, txg = tid & 3;
    const int bz = blockIdx.z;               // ((b*2+half)<<3) | zt
    const int zt = bz & 7, bh = bz >> 3;
    const int b = bh >> 1, half = bh & 1;
    const int z0 = zt * 8, y0 = blockIdx.y * 8, x0 = blockIdx.x * 16;

    stage20(hxo + (size_t)b * HHH, tile, z0, y0, x0, tid);
    __syncthreads();
    float4 pa[9]; float2 pb[9];
    loadnb(tile, tz, ty, txg, pa, pb);       // 18 vector LDS reads, reused x16

    const size_t vox = ((size_t)(z0 + tz) * 64 + (y0 + ty)) * 64 + (x0 + txg * 4);
    const float* xbase = (half ? x2 : x1) + (size_t)(b * 16) * HHH + vox;
    const float* wbase = w_fus + (half * 16) * 27;
    const float* bbase = b_fus + half * 16;

    unsigned zp[4][8];                       // [voxel][ci pair] packed bf16x2
#pragma unroll
    for (int cc = 0; cc < 16; ++cc) {
        float4 zero = {0.f, 0.f, 0.f, 0.f};
        float4 g = conv27r(pa, pb, wbase + cc * 27, zero);
        float4 xv = *(const float4*)(xbase + (size_t)cc * HHH);
        float bf = bbase[cc];
        unsigned short z0v = f2bf(zcalc(g.x, bf, xv.x));
        unsigned short z1v = f2bf(zcalc(g.y, bf, xv.y));
        unsigned short z2v = f2bf(zcalc(g.z, bf, xv.z));
        unsigned short z3v = f2bf(zcalc(g.w, bf, xv.w));
        int p = cc >> 1;
        if ((cc & 1) == 0) {
            zp[0][p] = z0v; zp[1][p] = z1v; zp[2][p] = z2v; zp[3][p] = z3v;
        } else {
            zp[0][p] |= (unsigned)z0v << 16; zp[1][p] |= (unsigned)z1v << 16;
            zp[2][p] |= (unsigned)z2v << 16; zp[3][p] |= (unsigned)z3v << 16;
        }
    }
    unsigned short* zo = Zb + ((size_t)bh * HHH + vox) * 16;
#pragma unroll
    for (int v = 0; v < 4; ++v) {
        uint4 lo = {zp[v][0], zp[v][1], zp[v][2], zp[v][3]};
        uint4 hi = {zp[v][4], zp[v][5], zp[v][6], zp[v][7]};
        *(uint4*)(zo + v * 16)     = lo;
        *(uint4*)(zo + v * 16 + 8) = hi;
    }
}

// ---------------- c1/c2: 16ch -> 16ch 3^3 conv via bf16 MFMA ----------------
// 512 threads, 8z tile (57.6KB LDS, 2 blocks/CU -> 16 waves/CU), precomputed wf.
__global__ __launch_bounds__(512) void k_convc_mfma(
    const unsigned short* __restrict__ Zb,
    const unsigned short* __restrict__ wpre,
    const float* __restrict__ b1, const float* __restrict__ b2,
    float* __restrict__ out)
{
    __shared__ __align__(16) unsigned short tile[1800 * 16];   // 57600 B: [pos][ci]
    const int tid = threadIdx.x;
    const int lane = tid & 63;
    const int wvid = tid >> 6;                      // 0..7
    const int bz = blockIdx.z;                      // b*16 + half*8 + zt, bz in [0,32)
    const int b = bz >> 4, half = (bz >> 3) & 1, z0 = (bz & 7) * 8;
    const int y0 = blockIdx.y * 8, x0 = blockIdx.x * 16;
    const float* bias = half ? b2 : b1;

    const int g = lane >> 4;
    const int cihalf = g & 1;
    const int tapsel = g >> 1;

    short8 wf[14];
    const short8* wp = (const short8*)wpre + (half * 14) * 64 + lane;
#pragma unroll
    for (int t = 0; t < 14; ++t) wf[t] = wp[t * 64];

    float bfrag[4];
#pragma unroll
    for (int r = 0; r < 4; ++r) bfrag[r] = bias[g * 4 + r];

    const unsigned short* zsrc = Zb + (size_t)(b * 2 + half) * HHH * 16;
    for (int i = tid; i < 3600; i += 512) {
        int pos = i >> 1, h = i & 1;
        int lz = pos / 180;
        int r2 = pos - lz * 180;
        int ly = r2 / 18, lx = r2 - ly * 18;
        int gz = z0 - 1 + lz, gy = y0 - 1 + ly, gx = x0 - 1 + lx;
        uint4 pk = {0u, 0u, 0u, 0u};
        if ((unsigned)(gz | gy | gx) < 64u) {
            size_t gvox = ((size_t)(gz * 64 + gy)) * 64 + gx;
            pk = *(const uint4*)(zsrc + gvox * 16 + h * 8);
        }
        *(uint4*)&tile[pos * 16 + h * 8] = pk;
    }
    __syncthreads();

    int offs[14];
#pragma unroll
    for (int t = 0; t < 14; ++t) {
        int tap = 2 * t + tapsel;
        int tcl = tap < 27 ? tap : 26;
        int dz = tcl / 9, rr = tcl - dz * 9;
        int dy = rr / 3, dx = rr - dy * 3;
        offs[t] = (((dz * 10 + dy) * 18 + dx + (lane & 15)) << 5) + (cihalf << 4);
    }

    const char* tb = (const char*)tile;
    for (int rr = 0; rr < 8; ++rr) {                 // 64 rows / 8 waves
        int rowid = wvid * 8 + rr;
        int zr = rowid >> 3, yr = rowid & 7;
        int rbase = ((zr * 10 + yr) * 18) << 5;
        f32x4 acc = {0.f, 0.f, 0.f, 0.f};
        f32x4 acc2 = {0.f, 0.f, 0.f, 0.f};
#pragma unroll
        for (int t = 0; t < 14; t += 2) {
            short8 bf0 = *(const short8*)(tb + (rbase + offs[t]));
            acc = __builtin_amdgcn_mfma_f32_16x16x32_bf16(wf[t], bf0, acc, 0, 0, 0);
            short8 bf1 = *(const short8*)(tb + (rbase + offs[t + 1]));
            acc2 = __builtin_amdgcn_mfma_f32_16x16x32_bf16(wf[t + 1], bf1, acc2, 0, 0, 0);
        }
        size_t vox = ((size_t)(z0 + zr) * 64 + (y0 + yr)) * 64 + x0 + (lane & 15);
        float* ob = out + (size_t)half * (2 * 16 * (size_t)HHH) + (size_t)(b * 16) * HHH + vox;
#pragma unroll
        for (int r = 0; r < 4; ++r) {
            float v = acc[r] + acc2[r] + bfrag[r];
            ob[(size_t)(g * 4 + r) * HHH] = fmaxf(v, 0.f);
        }
    }
}

extern "C" void kernel_launch(void* const* d_in, const int* in_sizes, int n_in,
                              void* d_out, int out_size, void* d_ws, size_t ws_size,
                              hipStream_t stream)
{
    const float* x1     = (const float*)d_in[0];
    const float* x2     = (const float*)d_in[1];
    const float* w_red  = (const float*)d_in[2];
    const float* b_red  = (const float*)d_in[3];
    const float* w_cx   = (const float*)d_in[4];
    const float* b_cx   = (const float*)d_in[5];
    const float* w_cy   = (const float*)d_in[6];
    const float* b_cy   = (const float*)d_in[7];
    const float* w_cz   = (const float*)d_in[8];
    const float* b_cz   = (const float*)d_in[9];
    const float* w_sp1  = (const float*)d_in[10];
    const float* b_sp1  = (const float*)d_in[11];
    const float* w_sp3  = (const float*)d_in[12];
    const float* b_sp3  = (const float*)d_in[13];
    const float* w_sp5a = (const float*)d_in[14];
    const float* b_sp5a = (const float*)d_in[15];
    const float* w_sp5b = (const float*)d_in[16];
    const float* b_sp5b = (const float*)d_in[17];
    const float* w_fus  = (const float*)d_in[18];
    const float* b_fus  = (const float*)d_in[19];
    const float* w_c1   = (const float*)d_in[20];
    const float* b_c1   = (const float*)d_in[21];
    const float* w_c2   = (const float*)d_in[22];
    const float* b_c2   = (const float*)d_in[23];

    float* ws  = (float*)d_ws;
    float* out = (float*)d_out;

    float* HX   = ws + OFF_HX;
    float* SP3  = ws + OFF_SP3;
    float* SP5A = ws + OFF_SP5A;
    float* SP5B = ws + OFF_SP5B;
    float* HXO  = ws + OFF_HXO;
    float* Qb   = ws + OFF_Q;
    float* Kb   = ws + OFF_K;
    float* Vb   = ws + OFF_V;
    float* XYZb = ws + OFF_XYZ;
    float* KM   = ws + OFF_KM;
    unsigned short* Zb   = (unsigned short*)(ws + OFF_Z);
    unsigned short* WPRE = (unsigned short*)(ws + OFF_WPRE);

    k_wprep    <<<7, 256, 0, stream>>>(w_c1, w_c2, WPRE);
    k_conv_red32<<<dim3(4, 8, 16), 256, 0, stream>>>(x1, x2, w_red, b_red, HX);
    k_conv1ch_dual<<<dim3(4, 8, 16), 256, 0, stream>>>(HX, w_sp3, b_sp3, SP3,
                                                       w_sp5a, b_sp5a, SP5A);
    k_conv1ch  <<<dim3(4, 8, 16), 256, 0, stream>>>(SP5A, w_sp5b, b_sp5b, SP5B);
    k_qk       <<<128, 256, 0, stream>>>(HX, w_cx, b_cx, w_cy, b_cy, Qb, Kb);
    k_v        <<<128, 256, 0, stream>>>(HX, w_cz, b_cz, Vb);
    k_kmax     <<<2, 256, 0, stream>>>(Kb, KM);
    k_xyz      <<<dim3(64, 2), 256, 0, stream>>>(Qb, Kb, Vb, KM, XYZb);
    k_attn     <<<128, 256, 0, stream>>>(HX, SP3, SP5B, XYZb, w_sp1, b_sp1, HXO);
    k_fuse_half<<<dim3(4, 8, 32), 256, 0, stream>>>(HXO, x1, x2, w_fus, b_fus, Zb);
    k_convc_mfma<<<dim3(4, 8, 32), 512, 0, stream>>>(Zb, WPRE, b_c1, b_c2, out);
}